// Round 15
// baseline (227.013 us; speedup 1.0000x reference)
//
#include <hip/hip_runtime.h>
#include <cstdint>
#include <type_traits>

// ReprogrammingLayer on MI355X (gfx950), round 15:
//  - single change vs round 14 (200.7 us): attention on the r11 2-buffer counted-vmcnt
//    schedule with 32 KB LDS and __launch_bounds__(256,5) -> 5 blocks/CU (was 3).
//    Rationale: attn is latency-bound (VGPR=84, MfmaUtil ~6%); occupancy is the lever.

typedef unsigned short u16;
typedef __attribute__((ext_vector_type(8))) short bf16x8;    // 8 bf16 = 4 VGPR (MFMA A/B frag)
typedef __attribute__((ext_vector_type(4))) float f32x4;     // 16x16 MFMA C/D frag
typedef __attribute__((ext_vector_type(16))) float f32x16;   // 32x32 MFMA C/D frag
typedef __attribute__((ext_vector_type(4))) float fvec4;
typedef __attribute__((ext_vector_type(4))) unsigned short u16x4;
typedef __attribute__((ext_vector_type(4))) unsigned int u32x4;
typedef __attribute__((ext_vector_type(2))) unsigned int u32x2;

using gld_src_t = const __attribute__((address_space(1))) void*;
using gld_dst_t = __attribute__((address_space(3))) void*;

static __device__ __forceinline__ u16 bf16_rne(float f) {
  uint32_t u = __builtin_bit_cast(uint32_t, f);
  u += 0x7fffu + ((u >> 16) & 1u);          // round-to-nearest-even
  return (u16)(u >> 16);
}

static __device__ __forceinline__ float exp2_fast(float x) {
  float r; asm("v_exp_f32 %0, %1" : "=v"(r) : "v"(x)); return r;   // HW exp2
}

static __device__ __forceinline__ uint32_t pk_bf16(float a, float b) {
  return (uint32_t)bf16_rne(a) | ((uint32_t)bf16_rne(b) << 16);   // a -> low, b -> high
}

// ---------------- fused fp32 -> bf16 converts (grid.y selects tensor) -----------------
__global__ void convert_all_bf16(const float* __restrict__ t0, u16* __restrict__ o0,
                                 const float* __restrict__ t1, u16* __restrict__ o1,
                                 const float* __restrict__ t2, u16* __restrict__ o2) {
  const int sel = blockIdx.y;
  const float* in = sel == 0 ? t0 : (sel == 1 ? t1 : t2);
  u16* out = sel == 0 ? o0 : (sel == 1 ? o1 : o2);
  const int C = sel == 0 ? 768 : 4096;
  const int validR = sel == 0 ? 8192 : 1000;
  const long n4 = sel == 0 ? (8192ll * 768 / 4) : (1024ll * 4096 / 4);

  long stride = (long)gridDim.x * blockDim.x;
  for (long i = (long)blockIdx.x * blockDim.x + threadIdx.x; i < n4; i += stride) {
    long e = i << 2;
    int r = (int)(e / C);
    u16x4 o;
    if (r < validR) {
      fvec4 v = *(const fvec4*)(in + e);
      o[0] = bf16_rne(v[0]); o[1] = bf16_rne(v[1]);
      o[2] = bf16_rne(v[2]); o[3] = bf16_rne(v[3]);
    } else {
      o[0] = 0; o[1] = 0; o[2] = 0; o[3] = 0;
    }
    *(u16x4*)(out + e) = o;
  }
}

// ---------------- transpose to bf16: in[R][C] fp32 -> out[C][R] bf16 (dual via z) ------
__global__ void transpose_to_bf16_f32(const float* __restrict__ in0, u16* __restrict__ out0,
                                      const float* __restrict__ in1, u16* __restrict__ out1,
                                      int R, int C) {
  const float* inv = blockIdx.z ? in1 : in0;
  u16* out = blockIdx.z ? out1 : out0;
  __shared__ u16 tile[32][33];
  int bc = blockIdx.x * 32, br = blockIdx.y * 32;
  int tx = threadIdx.x & 31, ty = threadIdx.x >> 5;
#pragma unroll
  for (int i = 0; i < 4; ++i) {
    int r = br + ty + i * 8, c = bc + tx;
    u16 bits = 0;
    if (r < R && c < C) bits = bf16_rne(inv[(size_t)r * C + c]);
    tile[ty + i * 8][tx] = bits;
  }
  __syncthreads();
#pragma unroll
  for (int i = 0; i < 4; ++i) {
    int orow = bc + ty + i * 8, oc = br + tx;
    if (orow < C && oc < R) out[(size_t)orow * R + oc] = tile[tx][ty + i * 8];
  }
}

// ---------------- 128x128-tile BK=64 dbuf GEMM (Q-projection; round-9 proven) ----------
template <typename CT>
__global__ __launch_bounds__(256, 2) void gemm_bt_128p(
    const u16* __restrict__ A, const u16* __restrict__ B,
    const float* __restrict__ bias, CT* __restrict__ C,
    int N, int K, float escale) {
  __shared__ u16 As[2][128 * 64];   // 2 x 16 KB
  __shared__ u16 Bs[2][128 * 64];   // 2 x 16 KB

  const int tid = threadIdx.x, lane = tid & 63, w = tid >> 6;
  const int lr = lane & 15, lg = lane >> 4;
  const int wr = (w >> 1) * 64, wc = (w & 1) * 64;

  const int nbx = N >> 7;
  const int bid = blockIdx.y * gridDim.x + blockIdx.x;
  const int cpx = (gridDim.x * gridDim.y) >> 3;
  const int swz = (bid & 7) * cpx + (bid >> 3);
  const int bm = (swz / nbx) * 128, bn = (swz % nbx) * 128;

  f32x4 acc[4][4] = {};

  auto STAGE = [&](int t, int buf) {
#pragma unroll
    for (int it = 0; it < 4; ++it) {
      const int s = it * 256 + tid;
      const int r = s >> 3;
      const int cg = (s & 7) ^ (r & 7);
      const int ldsb = (it * 256 + w * 64) * 16;
      __builtin_amdgcn_global_load_lds(
          (gld_src_t)(const void*)(A + (size_t)(bm + r) * K + t * 64 + cg * 8),
          (gld_dst_t)((char*)&As[buf][0] + ldsb), 16, 0, 0);
      __builtin_amdgcn_global_load_lds(
          (gld_src_t)(const void*)(B + (size_t)(bn + r) * K + t * 64 + cg * 8),
          (gld_dst_t)((char*)&Bs[buf][0] + ldsb), 16, 0, 0);
    }
  };

  auto LDF = [&](const u16* base, int R, int CB) {
    return *(const bf16x8*)((const char*)base + (size_t)R * 128 + (CB ^ ((R & 7) << 4)));
  };

  STAGE(0, 0);

  const int nk = K >> 6;
  for (int t = 0; t < nk; ++t) {
    const int cur = t & 1;
    if (t + 1 < nk) {
      STAGE(t + 1, cur ^ 1);
      asm volatile("s_waitcnt vmcnt(8)" ::: "memory");
    } else {
      asm volatile("s_waitcnt vmcnt(0)" ::: "memory");
    }
    __builtin_amdgcn_s_barrier();
    __builtin_amdgcn_sched_barrier(0);

    const u16* as = &As[cur][0];
    const u16* bs = &Bs[cur][0];

    bf16x8 af[4][2], bfr[4][2];
#pragma unroll
    for (int m = 0; m < 4; ++m)
#pragma unroll
      for (int kk = 0; kk < 2; ++kk)
        af[m][kk] = LDF(as, wr + m * 16 + lr, kk * 64 + lg * 16);
#pragma unroll
    for (int n = 0; n < 4; ++n)
#pragma unroll
      for (int kk = 0; kk < 2; ++kk)
        bfr[n][kk] = LDF(bs, wc + n * 16 + lr, kk * 64 + lg * 16);

    __builtin_amdgcn_s_setprio(1);
#pragma unroll
    for (int kk = 0; kk < 2; ++kk)
#pragma unroll
      for (int m = 0; m < 4; ++m)
#pragma unroll
        for (int n = 0; n < 4; ++n)
          acc[m][n] = __builtin_amdgcn_mfma_f32_16x16x32_bf16(
              af[m][kk], bfr[n][kk], acc[m][n], 0, 0, 0);
    __builtin_amdgcn_s_setprio(0);

    __builtin_amdgcn_sched_barrier(0);
    __builtin_amdgcn_s_barrier();
  }

#pragma unroll
  for (int n = 0; n < 4; ++n) {
    const int col = bn + wc + n * 16 + lr;
    const float bv = bias[col];
#pragma unroll
    for (int m = 0; m < 4; ++m) {
      const int row0 = bm + wr + m * 16 + lg * 4;
#pragma unroll
      for (int r = 0; r < 4; ++r) {
        float v = (acc[m][n][r] + bv) * escale;
        if constexpr (std::is_same<CT, u16>::value)
          C[(size_t)(row0 + r) * N + col] = bf16_rne(v);
        else
          C[(size_t)(row0 + r) * N + col] = v;
      }
    }
  }
}

// ---------------- split-K K/V projection, 128p structure (BK=64, dbuf, counted vmcnt) --
__global__ __launch_bounds__(256, 2) void gemm_kv_splitk_p(
    const u16* __restrict__ Sb, const u16* __restrict__ Vbi,
    const u16* __restrict__ WkT, const u16* __restrict__ WvT,
    float* __restrict__ part) {
  const int z = blockIdx.z;
  const u16* A = (z >> 2) ? Vbi : Sb;      // [1024][4096]
  const u16* B = (z >> 2) ? WvT : WkT;     // [768][4096]
  float* C = part + (size_t)z * (1024 * 768);
  const int kofs = (z & 3) * 1024;
  constexpr int K = 4096;

  __shared__ u16 As[2][128 * 64];
  __shared__ u16 Bs[2][128 * 64];

  const int tid = threadIdx.x, lane = tid & 63, w = tid >> 6;
  const int lr = lane & 15, lg = lane >> 4;
  const int wr = (w >> 1) * 64, wc = (w & 1) * 64;
  const int bm = blockIdx.y * 128, bn = blockIdx.x * 128;

  f32x4 acc[4][4] = {};

  auto STAGE = [&](int t, int buf) {
#pragma unroll
    for (int it = 0; it < 4; ++it) {
      const int s = it * 256 + tid;
      const int r = s >> 3;
      const int cg = (s & 7) ^ (r & 7);
      const int ldsb = (it * 256 + w * 64) * 16;
      __builtin_amdgcn_global_load_lds(
          (gld_src_t)(const void*)(A + (size_t)(bm + r) * K + kofs + t * 64 + cg * 8),
          (gld_dst_t)((char*)&As[buf][0] + ldsb), 16, 0, 0);
      __builtin_amdgcn_global_load_lds(
          (gld_src_t)(const void*)(B + (size_t)(bn + r) * K + kofs + t * 64 + cg * 8),
          (gld_dst_t)((char*)&Bs[buf][0] + ldsb), 16, 0, 0);
    }
  };

  auto LDF = [&](const u16* base, int R, int CB) {
    return *(const bf16x8*)((const char*)base + (size_t)R * 128 + (CB ^ ((R & 7) << 4)));
  };

  STAGE(0, 0);

  for (int t = 0; t < 16; ++t) {           // 1024 / 64
    const int cur = t & 1;
    if (t + 1 < 16) {
      STAGE(t + 1, cur ^ 1);
      asm volatile("s_waitcnt vmcnt(8)" ::: "memory");
    } else {
      asm volatile("s_waitcnt vmcnt(0)" ::: "memory");
    }
    __builtin_amdgcn_s_barrier();
    __builtin_amdgcn_sched_barrier(0);

    const u16* as = &As[cur][0];
    const u16* bs = &Bs[cur][0];

    bf16x8 af[4][2], bfr[4][2];
#pragma unroll
    for (int m = 0; m < 4; ++m)
#pragma unroll
      for (int kk = 0; kk < 2; ++kk)
        af[m][kk] = LDF(as, wr + m * 16 + lr, kk * 64 + lg * 16);
#pragma unroll
    for (int n = 0; n < 4; ++n)
#pragma unroll
      for (int kk = 0; kk < 2; ++kk)
        bfr[n][kk] = LDF(bs, wc + n * 16 + lr, kk * 64 + lg * 16);

    __builtin_amdgcn_s_setprio(1);
#pragma unroll
    for (int kk = 0; kk < 2; ++kk)
#pragma unroll
      for (int m = 0; m < 4; ++m)
#pragma unroll
        for (int n = 0; n < 4; ++n)
          acc[m][n] = __builtin_amdgcn_mfma_f32_16x16x32_bf16(
              af[m][kk], bfr[n][kk], acc[m][n], 0, 0, 0);
    __builtin_amdgcn_s_setprio(0);

    __builtin_amdgcn_sched_barrier(0);
    __builtin_amdgcn_s_barrier();
  }

#pragma unroll
  for (int n = 0; n < 4; ++n) {
    const int col = bn + wc + n * 16 + lr;
#pragma unroll
    for (int m = 0; m < 4; ++m) {
      const int row0 = bm + wr + m * 16 + lg * 4;
#pragma unroll
      for (int r = 0; r < 4; ++r)
        C[(size_t)(row0 + r) * 768 + col] = acc[m][n][r];
    }
  }
}

// ---------------- K reduce: partials + bias -> bf16 Kp [1024][768] ---------------------
__global__ __launch_bounds__(256) void kv_reduce_k(const float* __restrict__ part,
                                                   const float* __restrict__ bk,
                                                   u16* __restrict__ Kp) {
  const long e = ((long)blockIdx.x * 256 + threadIdx.x) * 4;
  const float* p0 = part + e;
  fvec4 s = *(const fvec4*)p0;
  s += *(const fvec4*)(p0 + 786432);
  s += *(const fvec4*)(p0 + 2 * 786432);
  s += *(const fvec4*)(p0 + 3 * 786432);
  int col = (int)(e % 768);
  s += *(const fvec4*)(bk + col);
  u16x4 o;
  o[0] = bf16_rne(s[0]); o[1] = bf16_rne(s[1]); o[2] = bf16_rne(s[2]); o[3] = bf16_rne(s[3]);
  *(u16x4*)(Kp + e) = o;
}

// ---------------- V reduce + transpose: partials + bias -> bf16 VTp [768][1024] --------
__global__ __launch_bounds__(256) void kv_reduce_vt(const float* __restrict__ part,
                                                    const float* __restrict__ bv,
                                                    u16* __restrict__ VTp) {
  __shared__ u16 tile[32][33];
  const float* pv = part + 4ull * 786432;
  const int c0 = blockIdx.x * 32, r0 = blockIdx.y * 32;
  const int tx = threadIdx.x & 31, ty = threadIdx.x >> 5;
#pragma unroll
  for (int i = 0; i < 4; ++i) {
    const int r = r0 + ty + i * 8, c = c0 + tx;
    const size_t idx = (size_t)r * 768 + c;
    float s = pv[idx] + pv[idx + 786432] + pv[idx + 2 * 786432] + pv[idx + 3 * 786432]
            + bv[c];
    tile[ty + i * 8][tx] = bf16_rne(s);
  }
  __syncthreads();
#pragma unroll
  for (int i = 0; i < 4; ++i) {
    const int vr = c0 + ty + i * 8;
    const int vc = r0 + tx;
    VTp[(size_t)vr * 1024 + vc] = tile[tx][ty + i * 8];
  }
}

// ---------------- 256x256-tile BK=32 fine-phase GEMM (O-projection; round-11 proven) ----
__global__ __launch_bounds__(512, 2) void gemm_bt_256p(
    const u16* __restrict__ A, const u16* __restrict__ B,
    const float* __restrict__ bias, float* __restrict__ C,
    int N, int K) {
  __shared__ u16 As[4][128 * 64];   // 4 x 16 KB
  __shared__ u16 Bs[4][128 * 64];   // 4 x 16 KB

  const int tid = threadIdx.x, lane = tid & 63, w = tid >> 6;
  const int lr = lane & 15, lg = lane >> 4;
  const int wr = w >> 2, wcol = w & 3;

  const int nbx = N >> 8;
  const int bid = blockIdx.y * gridDim.x + blockIdx.x;
  const int cpx = (gridDim.x * gridDim.y) >> 3;
  const int swz = (bid & 7) * cpx + (bid >> 3);
  const int bm = (swz / nbx) * 256, bn = (swz % nbx) * 256;

  f32x4 acc[8][4] = {};

  auto STAGE_UNIT = [&](int t, int buf, int mat) {
#pragma unroll
    for (int it = 0; it < 2; ++it) {
      const int s = it * 512 + tid;
      const int rp = s >> 3;
      const int cl = (s & 7) ^ (rp & 7);
      const int gr = (cl >> 2) * 128 + rp;
      const int gc = cl & 3;
      const int ldsb = (it * 512 + w * 64) * 16;
      const u16* src = (mat ? B : A) + (size_t)((mat ? bn : bm) + gr) * K + t * 32 + gc * 8;
      __builtin_amdgcn_global_load_lds((gld_src_t)(const void*)src,
          (gld_dst_t)((char*)(mat ? &Bs[buf][0] : &As[buf][0]) + ldsb), 16, 0, 0);
    }
  };

  auto LDF = [&](const u16* base, int gr, int klg) {
    const int byte = (gr & 127) * 128 + (((((gr >> 7) * 4 + klg) << 4)) ^ ((gr & 7) << 4));
    return *(const bf16x8*)((const char*)base + byte);
  };

  STAGE_UNIT(0, 0, 0); STAGE_UNIT(0, 0, 1);
  STAGE_UNIT(1, 1, 0); STAGE_UNIT(1, 1, 1);
  asm volatile("s_waitcnt vmcnt(4)" ::: "memory");
  __builtin_amdgcn_s_barrier();
  __builtin_amdgcn_sched_barrier(0);

  const int nk = K >> 5;   // 24
  bf16x8 bfr[4];
  for (int t = 0; t < nk; ++t) {
    const int cur = t & 3;
    const u16* as = &As[cur][0];
    const u16* bs = &Bs[cur][0];
#pragma unroll
    for (int p = 0; p < 2; ++p) {
      bf16x8 af[4];
#pragma unroll
      for (int m = 0; m < 4; ++m)
        af[m] = LDF(as, wr * 128 + (p * 4 + m) * 16 + lr, lg);
      if (p == 0) {
#pragma unroll
        for (int n = 0; n < 4; ++n)
          bfr[n] = LDF(bs, wcol * 64 + n * 16 + lr, lg);
      }
      if (t + 2 < nk) STAGE_UNIT(t + 2, (t + 2) & 3, p);
      if (p == 1) {
        if (t + 2 < nk)      asm volatile("s_waitcnt vmcnt(4)" ::: "memory");
        else if (t + 1 < nk) asm volatile("s_waitcnt vmcnt(0)" ::: "memory");
      }
      __builtin_amdgcn_s_barrier();
      __builtin_amdgcn_sched_barrier(0);
      __builtin_amdgcn_s_setprio(1);
#pragma unroll
      for (int m = 0; m < 4; ++m)
#pragma unroll
        for (int n = 0; n < 4; ++n)
          acc[p * 4 + m][n] = __builtin_amdgcn_mfma_f32_16x16x32_bf16(
              af[m], bfr[n], acc[p * 4 + m][n], 0, 0, 0);
      __builtin_amdgcn_s_setprio(0);
      __builtin_amdgcn_sched_barrier(0);
    }
  }

  float bv[4];
#pragma unroll
  for (int nf = 0; nf < 4; ++nf) bv[nf] = bias[bn + wcol * 64 + nf * 16 + lr];
#pragma unroll
  for (int mf = 0; mf < 8; ++mf) {
    const int row0 = bm + wr * 128 + mf * 16 + lg * 4;
#pragma unroll
    for (int nf = 0; nf < 4; ++nf) {
      const int col = bn + wcol * 64 + nf * 16 + lr;
#pragma unroll
      for (int r = 0; r < 4; ++r)
        C[(size_t)(row0 + r) * N + col] = acc[mf][nf][r] + bv[nf];
    }
  }
}

// ---------------- swapped-QK^T flash attention: 2-buffer, counted vmcnt, 5 blocks/CU ---
// r11 schedule: STAGE(ch+1) -> vmcnt(4) -> barrier -> compute(ch) -> barrier.
// LDS 32 KB -> 5 blocks/CU at __launch_bounds__(256,5) (VGPR ~84 measured, cap 102).
__global__ __launch_bounds__(256, 5) void attn_flash(
    const u16* __restrict__ Q,   // [8192, 768] bf16, pre-scaled
    const u16* __restrict__ Kb,  // [1024, 768] bf16 (rows >= 1000 are zero-padded)
    const u16* __restrict__ VT,  // [768, 1024] bf16
    u16* __restrict__ O) {       // [8192, 768] bf16
  constexpr int DM = 768, SPAD = 1024;
  __shared__ u16 Ks[2][64 * 64];    // 2 x 8 KB
  __shared__ u16 VTs[2][64 * 64];   // 2 x 8 KB

  const int tid = threadIdx.x, w = tid >> 6, lane = tid & 63;
  const int q5 = lane & 31, hi = lane >> 5, l7 = lane & 7;
  const int h = blockIdx.y;
  const int qrow = blockIdx.x * 128 + w * 32 + q5;

  bf16x8 qf[4];
#pragma unroll
  for (int dstep = 0; dstep < 4; ++dstep)
    qf[dstep] = *(const bf16x8*)(Q + (size_t)qrow * DM + h * 64 + dstep * 16 + hi * 8);

  auto STAGE = [&](int ch, int buf) {   // 4 global_load_lds per thread
#pragma unroll
    for (int it = 0; it < 2; ++it) {
      int slot = it * 256 + w * 64 + lane;
      int row = slot >> 3;
      int cg = (slot & 7) ^ (row & 7);
      __builtin_amdgcn_global_load_lds(
          (gld_src_t)(const void*)(Kb + (size_t)(ch * 64 + row) * DM + h * 64 + cg * 8),
          (gld_dst_t)(&Ks[buf][(size_t)(it * 256 + w * 64) * 8]), 16, 0, 0);
      __builtin_amdgcn_global_load_lds(
          (gld_src_t)(const void*)(VT + (size_t)(h * 64 + row) * SPAD + ch * 64 + cg * 8),
          (gld_dst_t)(&VTs[buf][(size_t)(it * 256 + w * 64) * 8]), 16, 0, 0);
    }
  };

  STAGE(0, 0);

  float m_run = -3.0e38f, l_part = 0.0f;
  f32x16 oa0 = {}, oa1 = {};

  for (int ch = 0; ch < 16; ++ch) {
    const int cur = ch & 1;
    if (ch < 15) {
      STAGE(ch + 1, cur ^ 1);
      asm volatile("s_waitcnt vmcnt(4)" ::: "memory");   // stage(ch) landed; ch+1 in flight
    } else {
      asm volatile("s_waitcnt vmcnt(0)" ::: "memory");
    }
    __builtin_amdgcn_s_barrier();
    __builtin_amdgcn_sched_barrier(0);

    const char* kbase = (const char*)&Ks[cur][0];
    const char* vbase = (const char*)&VTs[cur][0];

    f32x16 sc0 = {}, sc1 = {};
#pragma unroll
    for (int dstep = 0; dstep < 4; ++dstep) {
      const int colb = (dstep * 32 + hi * 16);
      bf16x8 kf0 = *(const bf16x8*)(kbase + (size_t)q5 * 128 + (colb ^ (l7 << 4)));
      bf16x8 kf1 = *(const bf16x8*)(kbase + (size_t)(32 + q5) * 128 + (colb ^ (l7 << 4)));
      sc0 = __builtin_amdgcn_mfma_f32_32x32x16_bf16(kf0, qf[dstep], sc0, 0, 0, 0);
      sc1 = __builtin_amdgcn_mfma_f32_32x32x16_bf16(kf1, qf[dstep], sc1, 0, 0, 0);
    }
    if (ch == 15) {   // mask s >= 1000 (chunk 15, tile 1, regs r>=4)
#pragma unroll
      for (int r = 4; r < 16; ++r) sc1[r] = -3.0e38f;
    }

    float mi = sc0[0];
#pragma unroll
    for (int r = 1; r < 16; ++r) mi = fmaxf(mi, sc0[r]);
#pragma unroll
    for (int r = 0; r < 16; ++r) mi = fmaxf(mi, sc1[r]);
    float cm = fmaxf(mi, __shfl_xor(mi, 32, 64));

    if (__any(cm > m_run + 8.0f)) {        // defer-max (T13)
      float mn = fmaxf(m_run, cm);
      float fsc = exp2_fast(m_run - mn);
      m_run = mn;
      l_part *= fsc;
#pragma unroll
      for (int r = 0; r < 16; ++r) { oa0[r] *= fsc; oa1[r] *= fsc; }
    }

#pragma unroll
    for (int r = 0; r < 16; ++r) {
      float p0 = exp2_fast(sc0[r] - m_run); l_part += p0; sc0[r] = p0;
      float p1 = exp2_fast(sc1[r] - m_run); l_part += p1; sc1[r] = p1;
    }

#pragma unroll
    for (int st = 0; st < 2; ++st) {
#pragma unroll
      for (int ks = 0; ks < 2; ++ks) {
        float pv0, pv1, pv2, pv3, pv4, pv5, pv6, pv7;
        if (st == 0) {
          if (ks == 0) { pv0=sc0[0];pv1=sc0[1];pv2=sc0[2];pv3=sc0[3];pv4=sc0[4];pv5=sc0[5];pv6=sc0[6];pv7=sc0[7]; }
          else         { pv0=sc0[8];pv1=sc0[9];pv2=sc0[10];pv3=sc0[11];pv4=sc0[12];pv5=sc0[13];pv6=sc0[14];pv7=sc0[15]; }
        } else {
          if (ks == 0) { pv0=sc1[0];pv1=sc1[1];pv2=sc1[2];pv3=sc1[3];pv4=sc1[4];pv5=sc1[5];pv6=sc1[6];pv7=sc1[7]; }
          else         { pv0=sc1[8];pv1=sc1[9];pv2=sc1[10];pv3=sc1[11];pv4=sc1[12];pv5=sc1[13];pv6=sc1[14];pv7=sc1[15]; }
        }
        uint32_t a = pk_bf16(pv0, pv1), b = pk_bf16(pv2, pv3);
        uint32_t c = pk_bf16(pv4, pv5), d = pk_bf16(pv6, pv7);
        uint32_t sa = (uint32_t)__shfl_xor((int)a, 32, 64);
        uint32_t sb = (uint32_t)__shfl_xor((int)b, 32, 64);
        uint32_t sc_ = (uint32_t)__shfl_xor((int)c, 32, 64);
        uint32_t sd = (uint32_t)__shfl_xor((int)d, 32, 64);
        u32x4 jw;
        jw[0] = hi ? sc_ : a;
        jw[1] = hi ? sd  : b;
        jw[2] = hi ? c   : sa;
        jw[3] = hi ? d   : sb;
        bf16x8 pB = __builtin_bit_cast(bf16x8, jw);
        const int colb = (st * 64 + ks * 32 + hi * 16);
#pragma unroll
        for (int dt = 0; dt < 2; ++dt) {
          bf16x8 vtf = *(const bf16x8*)(vbase + (size_t)(dt * 32 + q5) * 128 + (colb ^ (l7 << 4)));
          if (dt == 0) oa0 = __builtin_amdgcn_mfma_f32_32x32x16_bf16(vtf, pB, oa0, 0, 0, 0);
          else         oa1 = __builtin_amdgcn_mfma_f32_32x32x16_bf16(vtf, pB, oa1, 0, 0, 0);
        }
      }
    }
    __builtin_amdgcn_sched_barrier(0);
    __builtin_amdgcn_s_barrier();            // buffer handoff
  }

  float ool = 1.0f / (l_part + __shfl_xor(l_part, 32, 64));
  u16* obase = O + (size_t)qrow * DM + h * 64;
#pragma unroll
  for (int dt = 0; dt < 2; ++dt) {
#pragma unroll
    for (int g = 0; g < 4; ++g) {
      float v0, v1, v2, v3;
      if (dt == 0) { v0 = oa0[4*g]; v1 = oa0[4*g+1]; v2 = oa0[4*g+2]; v3 = oa0[4*g+3]; }
      else         { v0 = oa1[4*g]; v1 = oa1[4*g+1]; v2 = oa1[4*g+2]; v3 = oa1[4*g+3]; }
      u32x2 st2;
      st2[0] = pk_bf16(v0 * ool, v1 * ool);
      st2[1] = pk_bf16(v2 * ool, v3 * ool);
      *(u32x2*)(obase + dt * 32 + g * 8 + hi * 4) = st2;
    }
  }
}

// ---------------- host ----------------
extern "C" void kernel_launch(void* const* d_in, const int* in_sizes, int n_in,
                              void* d_out, int out_size, void* d_ws, size_t ws_size,
                              hipStream_t stream) {
  (void)in_sizes; (void)n_in; (void)out_size; (void)ws_size;
  const float* target = (const float*)d_in[0];
  const float* source = (const float*)d_in[1];
  const float* value  = (const float*)d_in[2];
  const float* Wq = (const float*)d_in[3];
  const float* bq = (const float*)d_in[4];
  const float* Wk = (const float*)d_in[5];
  const float* bk = (const float*)d_in[6];
  const float* Wv = (const float*)d_in[7];
  const float* bv = (const float*)d_in[8];
  const float* Wo = (const float*)d_in[9];
  const float* bo = (const float*)d_in[10];
  float* out = (float*)d_out;

  char* ws = (char*)d_ws;
  size_t off = 0;
  auto carve = [&](size_t bytes) { void* p = ws + off; off += (bytes + 255) & ~(size_t)255; return p; };
  u16* Xb  = (u16*)carve(8192ull * 768 * 2);
  u16* Sb  = (u16*)carve(1024ull * 4096 * 2);
  u16* Vbi = (u16*)carve(1024ull * 4096 * 2);
  u16* WqT = (u16*)carve(768ull * 768 * 2);
  u16* WkT = (u16*)carve(768ull * 4096 * 2);
  u16* WvT = (u16*)carve(768ull * 4096 * 2);
  u16* WoT = (u16*)carve(4096ull * 768 * 2);
  u16* Qb  = (u16*)carve(8192ull * 768 * 2);
  u16* Kp  = (u16*)carve(1024ull * 768 * 2);
  u16* VTp = (u16*)carve(768ull * 1024 * 2);
  u16* Ob  = (u16*)carve(8192ull * 768 * 2);

  const float SCL = 0.18033688011112042f;   // (1/8) * log2(e): exp2-domain scores

  convert_all_bf16<<<dim3(1024, 3), 256, 0, stream>>>(target, Xb, source, Sb, value, Vbi);
  transpose_to_bf16_f32<<<dim3(24, 24, 1),  256, 0, stream>>>(Wq, WqT, Wq, WqT, 768, 768);
  transpose_to_bf16_f32<<<dim3(24, 128, 2), 256, 0, stream>>>(Wk, WkT, Wv, WvT, 4096, 768);
  transpose_to_bf16_f32<<<dim3(128, 24, 1), 256, 0, stream>>>(Wo, WoT, Wo, WoT, 768, 4096);

  gemm_kv_splitk_p<<<dim3(6, 8, 8), 256, 0, stream>>>(Sb, Vbi, WkT, WvT, out);
  kv_reduce_k<<<768, 256, 0, stream>>>(out, bk, Kp);
  kv_reduce_vt<<<dim3(24, 32), 256, 0, stream>>>(out, bv, VTp);

  gemm_bt_128p<u16><<<dim3(6, 64), 256, 0, stream>>>(Xb, WqT, bq, Qb, 768, 768, SCL);

  attn_flash<<<dim3(64, 12), 256, 0, stream>>>(Qb, Kp, VTp, Ob);

  gemm_bt_256p<<<dim3(16, 32), 512, 0, stream>>>(Ob, WoT, bo, out, 4096, 768);
}

// Round 16
// 190.605 us; speedup vs baseline: 1.1910x; 1.1910x over previous
//
#include <hip/hip_runtime.h>
#include <cstdint>
#include <type_traits>

// ReprogrammingLayer on MI355X (gfx950), round 16:
//  - attention reverted to round-14 exact (3-ring, launch_bounds(256,3)) after the r15
//    VGPR-cliff spill (bounds(256,5) forced VGPR 84->48 + scratch; occupancy steps are
//    64/128/256 per m69 -- 5 blocks/CU unreachable without spill).
//  - launch consolidation: preprocess_all (convert + 4 weight transposes, 1 launch) and
//    kv_reduce_all (K-reduce + V-reduce-transpose, 1 launch). 9 -> 6 launches.

typedef unsigned short u16;
typedef __attribute__((ext_vector_type(8))) short bf16x8;    // 8 bf16 = 4 VGPR (MFMA A/B frag)
typedef __attribute__((ext_vector_type(4))) float f32x4;     // 16x16 MFMA C/D frag
typedef __attribute__((ext_vector_type(16))) float f32x16;   // 32x32 MFMA C/D frag
typedef __attribute__((ext_vector_type(4))) float fvec4;
typedef __attribute__((ext_vector_type(4))) unsigned short u16x4;
typedef __attribute__((ext_vector_type(4))) unsigned int u32x4;
typedef __attribute__((ext_vector_type(2))) unsigned int u32x2;

using gld_src_t = const __attribute__((address_space(1))) void*;
using gld_dst_t = __attribute__((address_space(3))) void*;

static __device__ __forceinline__ u16 bf16_rne(float f) {
  uint32_t u = __builtin_bit_cast(uint32_t, f);
  u += 0x7fffu + ((u >> 16) & 1u);          // round-to-nearest-even
  return (u16)(u >> 16);
}

static __device__ __forceinline__ float exp2_fast(float x) {
  float r; asm("v_exp_f32 %0, %1" : "=v"(r) : "v"(x)); return r;   // HW exp2
}

static __device__ __forceinline__ uint32_t pk_bf16(float a, float b) {
  return (uint32_t)bf16_rne(a) | ((uint32_t)bf16_rne(b) << 16);   // a -> low, b -> high
}

// ---------------- fused preprocessing: converts + all 4 weight transposes --------------
// blocks [0,3072): fp32->bf16 converts (1024 per tensor, grid-stride);
// blocks [3072,...): 32x32 transpose tiles: Wq 576, Wk 3072, Wv 3072, Wo 3072.
__global__ void preprocess_all(
    const float* __restrict__ target, u16* __restrict__ Xb,
    const float* __restrict__ source, u16* __restrict__ Sb,
    const float* __restrict__ value,  u16* __restrict__ Vbi,
    const float* __restrict__ Wq, u16* __restrict__ WqT,
    const float* __restrict__ Wk, u16* __restrict__ WkT,
    const float* __restrict__ Wv, u16* __restrict__ WvT,
    const float* __restrict__ Wo, u16* __restrict__ WoT) {
  __shared__ u16 tile[32][33];
  const int bi = blockIdx.x, tid = threadIdx.x;

  if (bi < 3072) {   // converts
    const int sel = bi >> 10;          // 0: target, 1: source, 2: value
    const int ib = bi & 1023;
    const float* in = sel == 0 ? target : (sel == 1 ? source : value);
    u16* out = sel == 0 ? Xb : (sel == 1 ? Sb : Vbi);
    const int C = sel == 0 ? 768 : 4096;
    const int validR = sel == 0 ? 8192 : 1000;
    const long n4 = sel == 0 ? (8192ll * 768 / 4) : (1024ll * 4096 / 4);
    const long stride = 1024ll * 256;
    for (long i = (long)ib * 256 + tid; i < n4; i += stride) {
      long e = i << 2;
      int r = (int)(e / C);
      u16x4 o;
      if (r < validR) {
        fvec4 v = *(const fvec4*)(in + e);
        o[0] = bf16_rne(v[0]); o[1] = bf16_rne(v[1]);
        o[2] = bf16_rne(v[2]); o[3] = bf16_rne(v[3]);
      } else {
        o[0] = 0; o[1] = 0; o[2] = 0; o[3] = 0;
      }
      *(u16x4*)(out + e) = o;
    }
    return;
  }

  // weight transposes: in[R][C] fp32 -> out[C][R] bf16
  int j = bi - 3072;
  const float* inv; u16* out; int R, C, bx, by;
  if (j < 576)        { inv = Wq; out = WqT; R = 768;  C = 768;  bx = j % 24;  by = j / 24; }
  else if (j < 3648)  { j -= 576;  inv = Wk; out = WkT; R = 4096; C = 768; bx = j % 24; by = j / 24; }
  else if (j < 6720)  { j -= 3648; inv = Wv; out = WvT; R = 4096; C = 768; bx = j % 24; by = j / 24; }
  else                { j -= 6720; inv = Wo; out = WoT; R = 768;  C = 4096; bx = j % 128; by = j / 128; }
  const int bc = bx * 32, br = by * 32;
  const int tx = tid & 31, ty = tid >> 5;
#pragma unroll
  for (int i = 0; i < 4; ++i) {
    int r = br + ty + i * 8, c = bc + tx;
    u16 bits = 0;
    if (r < R && c < C) bits = bf16_rne(inv[(size_t)r * C + c]);
    tile[ty + i * 8][tx] = bits;
  }
  __syncthreads();
#pragma unroll
  for (int i = 0; i < 4; ++i) {
    int orow = bc + ty + i * 8, oc = br + tx;
    if (orow < C && oc < R) out[(size_t)orow * R + oc] = tile[tx][ty + i * 8];
  }
}

// ---------------- 128x128-tile BK=64 dbuf GEMM (Q-projection; round-9 proven) ----------
template <typename CT>
__global__ __launch_bounds__(256, 2) void gemm_bt_128p(
    const u16* __restrict__ A, const u16* __restrict__ B,
    const float* __restrict__ bias, CT* __restrict__ C,
    int N, int K, float escale) {
  __shared__ u16 As[2][128 * 64];   // 2 x 16 KB
  __shared__ u16 Bs[2][128 * 64];   // 2 x 16 KB

  const int tid = threadIdx.x, lane = tid & 63, w = tid >> 6;
  const int lr = lane & 15, lg = lane >> 4;
  const int wr = (w >> 1) * 64, wc = (w & 1) * 64;

  const int nbx = N >> 7;
  const int bid = blockIdx.y * gridDim.x + blockIdx.x;
  const int cpx = (gridDim.x * gridDim.y) >> 3;
  const int swz = (bid & 7) * cpx + (bid >> 3);
  const int bm = (swz / nbx) * 128, bn = (swz % nbx) * 128;

  f32x4 acc[4][4] = {};

  auto STAGE = [&](int t, int buf) {
#pragma unroll
    for (int it = 0; it < 4; ++it) {
      const int s = it * 256 + tid;
      const int r = s >> 3;
      const int cg = (s & 7) ^ (r & 7);
      const int ldsb = (it * 256 + w * 64) * 16;
      __builtin_amdgcn_global_load_lds(
          (gld_src_t)(const void*)(A + (size_t)(bm + r) * K + t * 64 + cg * 8),
          (gld_dst_t)((char*)&As[buf][0] + ldsb), 16, 0, 0);
      __builtin_amdgcn_global_load_lds(
          (gld_src_t)(const void*)(B + (size_t)(bn + r) * K + t * 64 + cg * 8),
          (gld_dst_t)((char*)&Bs[buf][0] + ldsb), 16, 0, 0);
    }
  };

  auto LDF = [&](const u16* base, int R, int CB) {
    return *(const bf16x8*)((const char*)base + (size_t)R * 128 + (CB ^ ((R & 7) << 4)));
  };

  STAGE(0, 0);

  const int nk = K >> 6;
  for (int t = 0; t < nk; ++t) {
    const int cur = t & 1;
    if (t + 1 < nk) {
      STAGE(t + 1, cur ^ 1);
      asm volatile("s_waitcnt vmcnt(8)" ::: "memory");
    } else {
      asm volatile("s_waitcnt vmcnt(0)" ::: "memory");
    }
    __builtin_amdgcn_s_barrier();
    __builtin_amdgcn_sched_barrier(0);

    const u16* as = &As[cur][0];
    const u16* bs = &Bs[cur][0];

    bf16x8 af[4][2], bfr[4][2];
#pragma unroll
    for (int m = 0; m < 4; ++m)
#pragma unroll
      for (int kk = 0; kk < 2; ++kk)
        af[m][kk] = LDF(as, wr + m * 16 + lr, kk * 64 + lg * 16);
#pragma unroll
    for (int n = 0; n < 4; ++n)
#pragma unroll
      for (int kk = 0; kk < 2; ++kk)
        bfr[n][kk] = LDF(bs, wc + n * 16 + lr, kk * 64 + lg * 16);

    __builtin_amdgcn_s_setprio(1);
#pragma unroll
    for (int kk = 0; kk < 2; ++kk)
#pragma unroll
      for (int m = 0; m < 4; ++m)
#pragma unroll
        for (int n = 0; n < 4; ++n)
          acc[m][n] = __builtin_amdgcn_mfma_f32_16x16x32_bf16(
              af[m][kk], bfr[n][kk], acc[m][n], 0, 0, 0);
    __builtin_amdgcn_s_setprio(0);

    __builtin_amdgcn_sched_barrier(0);
    __builtin_amdgcn_s_barrier();
  }

#pragma unroll
  for (int n = 0; n < 4; ++n) {
    const int col = bn + wc + n * 16 + lr;
    const float bv = bias[col];
#pragma unroll
    for (int m = 0; m < 4; ++m) {
      const int row0 = bm + wr + m * 16 + lg * 4;
#pragma unroll
      for (int r = 0; r < 4; ++r) {
        float v = (acc[m][n][r] + bv) * escale;
        if constexpr (std::is_same<CT, u16>::value)
          C[(size_t)(row0 + r) * N + col] = bf16_rne(v);
        else
          C[(size_t)(row0 + r) * N + col] = v;
      }
    }
  }
}

// ---------------- split-K K/V projection, 128p structure (BK=64, dbuf, counted vmcnt) --
__global__ __launch_bounds__(256, 2) void gemm_kv_splitk_p(
    const u16* __restrict__ Sb, const u16* __restrict__ Vbi,
    const u16* __restrict__ WkT, const u16* __restrict__ WvT,
    float* __restrict__ part) {
  const int z = blockIdx.z;
  const u16* A = (z >> 2) ? Vbi : Sb;      // [1024][4096]
  const u16* B = (z >> 2) ? WvT : WkT;     // [768][4096]
  float* C = part + (size_t)z * (1024 * 768);
  const int kofs = (z & 3) * 1024;
  constexpr int K = 4096;

  __shared__ u16 As[2][128 * 64];
  __shared__ u16 Bs[2][128 * 64];

  const int tid = threadIdx.x, lane = tid & 63, w = tid >> 6;
  const int lr = lane & 15, lg = lane >> 4;
  const int wr = (w >> 1) * 64, wc = (w & 1) * 64;
  const int bm = blockIdx.y * 128, bn = blockIdx.x * 128;

  f32x4 acc[4][4] = {};

  auto STAGE = [&](int t, int buf) {
#pragma unroll
    for (int it = 0; it < 4; ++it) {
      const int s = it * 256 + tid;
      const int r = s >> 3;
      const int cg = (s & 7) ^ (r & 7);
      const int ldsb = (it * 256 + w * 64) * 16;
      __builtin_amdgcn_global_load_lds(
          (gld_src_t)(const void*)(A + (size_t)(bm + r) * K + kofs + t * 64 + cg * 8),
          (gld_dst_t)((char*)&As[buf][0] + ldsb), 16, 0, 0);
      __builtin_amdgcn_global_load_lds(
          (gld_src_t)(const void*)(B + (size_t)(bn + r) * K + kofs + t * 64 + cg * 8),
          (gld_dst_t)((char*)&Bs[buf][0] + ldsb), 16, 0, 0);
    }
  };

  auto LDF = [&](const u16* base, int R, int CB) {
    return *(const bf16x8*)((const char*)base + (size_t)R * 128 + (CB ^ ((R & 7) << 4)));
  };

  STAGE(0, 0);

  for (int t = 0; t < 16; ++t) {           // 1024 / 64
    const int cur = t & 1;
    if (t + 1 < 16) {
      STAGE(t + 1, cur ^ 1);
      asm volatile("s_waitcnt vmcnt(8)" ::: "memory");
    } else {
      asm volatile("s_waitcnt vmcnt(0)" ::: "memory");
    }
    __builtin_amdgcn_s_barrier();
    __builtin_amdgcn_sched_barrier(0);

    const u16* as = &As[cur][0];
    const u16* bs = &Bs[cur][0];

    bf16x8 af[4][2], bfr[4][2];
#pragma unroll
    for (int m = 0; m < 4; ++m)
#pragma unroll
      for (int kk = 0; kk < 2; ++kk)
        af[m][kk] = LDF(as, wr + m * 16 + lr, kk * 64 + lg * 16);
#pragma unroll
    for (int n = 0; n < 4; ++n)
#pragma unroll
      for (int kk = 0; kk < 2; ++kk)
        bfr[n][kk] = LDF(bs, wc + n * 16 + lr, kk * 64 + lg * 16);

    __builtin_amdgcn_s_setprio(1);
#pragma unroll
    for (int kk = 0; kk < 2; ++kk)
#pragma unroll
      for (int m = 0; m < 4; ++m)
#pragma unroll
        for (int n = 0; n < 4; ++n)
          acc[m][n] = __builtin_amdgcn_mfma_f32_16x16x32_bf16(
              af[m][kk], bfr[n][kk], acc[m][n], 0, 0, 0);
    __builtin_amdgcn_s_setprio(0);

    __builtin_amdgcn_sched_barrier(0);
    __builtin_amdgcn_s_barrier();
  }

#pragma unroll
  for (int n = 0; n < 4; ++n) {
    const int col = bn + wc + n * 16 + lr;
#pragma unroll
    for (int m = 0; m < 4; ++m) {
      const int row0 = bm + wr + m * 16 + lg * 4;
#pragma unroll
      for (int r = 0; r < 4; ++r)
        C[(size_t)(row0 + r) * 768 + col] = acc[m][n][r];
    }
  }
}

// ---------------- fused reduces: blocks [0,768) K-reduce; [768,1536) V-reduce+transpose
__global__ __launch_bounds__(256) void kv_reduce_all(const float* __restrict__ part,
                                                     const float* __restrict__ bk,
                                                     const float* __restrict__ bv,
                                                     u16* __restrict__ Kp,
                                                     u16* __restrict__ VTp) {
  __shared__ u16 tile[32][33];
  const int bi = blockIdx.x;
  if (bi < 768) {   // K reduce: partials z=0..3 + bias -> bf16 Kp [1024][768]
    const long e = ((long)bi * 256 + threadIdx.x) * 4;
    const float* p0 = part + e;
    fvec4 s = *(const fvec4*)p0;
    s += *(const fvec4*)(p0 + 786432);
    s += *(const fvec4*)(p0 + 2 * 786432);
    s += *(const fvec4*)(p0 + 3 * 786432);
    int col = (int)(e % 768);
    s += *(const fvec4*)(bk + col);
    u16x4 o;
    o[0] = bf16_rne(s[0]); o[1] = bf16_rne(s[1]); o[2] = bf16_rne(s[2]); o[3] = bf16_rne(s[3]);
    *(u16x4*)(Kp + e) = o;
    return;
  }
  // V reduce + transpose: partials z=4..7 + bias -> bf16 VTp [768][1024]
  const int j = bi - 768;
  const float* pv = part + 4ull * 786432;
  const int c0 = (j % 24) * 32, r0 = (j / 24) * 32;
  const int tx = threadIdx.x & 31, ty = threadIdx.x >> 5;
#pragma unroll
  for (int i = 0; i < 4; ++i) {
    const int r = r0 + ty + i * 8, c = c0 + tx;
    const size_t idx = (size_t)r * 768 + c;
    float s = pv[idx] + pv[idx + 786432] + pv[idx + 2 * 786432] + pv[idx + 3 * 786432]
            + bv[c];
    tile[ty + i * 8][tx] = bf16_rne(s);
  }
  __syncthreads();
#pragma unroll
  for (int i = 0; i < 4; ++i) {
    const int vr = c0 + ty + i * 8;
    const int vc = r0 + tx;
    VTp[(size_t)vr * 1024 + vc] = tile[tx][ty + i * 8];
  }
}

// ---------------- 256x256-tile BK=32 fine-phase GEMM (O-projection; round-11 proven) ----
__global__ __launch_bounds__(512, 2) void gemm_bt_256p(
    const u16* __restrict__ A, const u16* __restrict__ B,
    const float* __restrict__ bias, float* __restrict__ C,
    int N, int K) {
  __shared__ u16 As[4][128 * 64];   // 4 x 16 KB
  __shared__ u16 Bs[4][128 * 64];   // 4 x 16 KB

  const int tid = threadIdx.x, lane = tid & 63, w = tid >> 6;
  const int lr = lane & 15, lg = lane >> 4;
  const int wr = w >> 2, wcol = w & 3;

  const int nbx = N >> 8;
  const int bid = blockIdx.y * gridDim.x + blockIdx.x;
  const int cpx = (gridDim.x * gridDim.y) >> 3;
  const int swz = (bid & 7) * cpx + (bid >> 3);
  const int bm = (swz / nbx) * 256, bn = (swz % nbx) * 256;

  f32x4 acc[8][4] = {};

  auto STAGE_UNIT = [&](int t, int buf, int mat) {
#pragma unroll
    for (int it = 0; it < 2; ++it) {
      const int s = it * 512 + tid;
      const int rp = s >> 3;
      const int cl = (s & 7) ^ (rp & 7);
      const int gr = (cl >> 2) * 128 + rp;
      const int gc = cl & 3;
      const int ldsb = (it * 512 + w * 64) * 16;
      const u16* src = (mat ? B : A) + (size_t)((mat ? bn : bm) + gr) * K + t * 32 + gc * 8;
      __builtin_amdgcn_global_load_lds((gld_src_t)(const void*)src,
          (gld_dst_t)((char*)(mat ? &Bs[buf][0] : &As[buf][0]) + ldsb), 16, 0, 0);
    }
  };

  auto LDF = [&](const u16* base, int gr, int klg) {
    const int byte = (gr & 127) * 128 + (((((gr >> 7) * 4 + klg) << 4)) ^ ((gr & 7) << 4));
    return *(const bf16x8*)((const char*)base + byte);
  };

  STAGE_UNIT(0, 0, 0); STAGE_UNIT(0, 0, 1);
  STAGE_UNIT(1, 1, 0); STAGE_UNIT(1, 1, 1);
  asm volatile("s_waitcnt vmcnt(4)" ::: "memory");
  __builtin_amdgcn_s_barrier();
  __builtin_amdgcn_sched_barrier(0);

  const int nk = K >> 5;   // 24
  bf16x8 bfr[4];
  for (int t = 0; t < nk; ++t) {
    const int cur = t & 3;
    const u16* as = &As[cur][0];
    const u16* bs = &Bs[cur][0];
#pragma unroll
    for (int p = 0; p < 2; ++p) {
      bf16x8 af[4];
#pragma unroll
      for (int m = 0; m < 4; ++m)
        af[m] = LDF(as, wr * 128 + (p * 4 + m) * 16 + lr, lg);
      if (p == 0) {
#pragma unroll
        for (int n = 0; n < 4; ++n)
          bfr[n] = LDF(bs, wcol * 64 + n * 16 + lr, lg);
      }
      if (t + 2 < nk) STAGE_UNIT(t + 2, (t + 2) & 3, p);
      if (p == 1) {
        if (t + 2 < nk)      asm volatile("s_waitcnt vmcnt(4)" ::: "memory");
        else if (t + 1 < nk) asm volatile("s_waitcnt vmcnt(0)" ::: "memory");
      }
      __builtin_amdgcn_s_barrier();
      __builtin_amdgcn_sched_barrier(0);
      __builtin_amdgcn_s_setprio(1);
#pragma unroll
      for (int m = 0; m < 4; ++m)
#pragma unroll
        for (int n = 0; n < 4; ++n)
          acc[p * 4 + m][n] = __builtin_amdgcn_mfma_f32_16x16x32_bf16(
              af[m], bfr[n], acc[p * 4 + m][n], 0, 0, 0);
      __builtin_amdgcn_s_setprio(0);
      __builtin_amdgcn_sched_barrier(0);
    }
  }

  float bv[4];
#pragma unroll
  for (int nf = 0; nf < 4; ++nf) bv[nf] = bias[bn + wcol * 64 + nf * 16 + lr];
#pragma unroll
  for (int mf = 0; mf < 8; ++mf) {
    const int row0 = bm + wr * 128 + mf * 16 + lg * 4;
#pragma unroll
    for (int nf = 0; nf < 4; ++nf) {
      const int col = bn + wcol * 64 + nf * 16 + lr;
#pragma unroll
      for (int r = 0; r < 4; ++r)
        C[(size_t)(row0 + r) * N + col] = acc[mf][nf][r] + bv[nf];
    }
  }
}

// ---------------- swapped-QK^T flash attention (round-14 exact: 3-ring, 1 barrier) -----
__global__ __launch_bounds__(256, 3) void attn_flash(
    const u16* __restrict__ Q,   // [8192, 768] bf16, pre-scaled
    const u16* __restrict__ Kb,  // [1024, 768] bf16 (rows >= 1000 are zero-padded)
    const u16* __restrict__ VT,  // [768, 1024] bf16
    u16* __restrict__ O) {       // [8192, 768] bf16
  constexpr int DM = 768, SPAD = 1024;
  __shared__ u16 Ks[3][64 * 64];    // 3 x 8 KB
  __shared__ u16 VTs[3][64 * 64];   // 3 x 8 KB

  const int tid = threadIdx.x, w = tid >> 6, lane = tid & 63;
  const int q5 = lane & 31, hi = lane >> 5, l7 = lane & 7;
  const int h = blockIdx.y;
  const int qrow = blockIdx.x * 128 + w * 32 + q5;

  bf16x8 qf[4];
#pragma unroll
  for (int dstep = 0; dstep < 4; ++dstep)
    qf[dstep] = *(const bf16x8*)(Q + (size_t)qrow * DM + h * 64 + dstep * 16 + hi * 8);

  auto STAGE = [&](int ch, int buf) {
#pragma unroll
    for (int it = 0; it < 2; ++it) {
      int slot = it * 256 + w * 64 + lane;
      int row = slot >> 3;
      int cg = (slot & 7) ^ (row & 7);
      __builtin_amdgcn_global_load_lds(
          (gld_src_t)(const void*)(Kb + (size_t)(ch * 64 + row) * DM + h * 64 + cg * 8),
          (gld_dst_t)(&Ks[buf][(size_t)(it * 256 + w * 64) * 8]), 16, 0, 0);
      __builtin_amdgcn_global_load_lds(
          (gld_src_t)(const void*)(VT + (size_t)(h * 64 + row) * SPAD + ch * 64 + cg * 8),
          (gld_dst_t)(&VTs[buf][(size_t)(it * 256 + w * 64) * 8]), 16, 0, 0);
    }
  };

  STAGE(0, 0);
  STAGE(1, 1);

  float m_run = -3.0e38f, l_part = 0.0f;
  f32x16 oa0 = {}, oa1 = {};

  for (int ch = 0; ch < 16; ++ch) {
    const int cur = ch % 3;
    if (ch < 15) asm volatile("s_waitcnt vmcnt(4)" ::: "memory");   // stage(ch) landed
    else         asm volatile("s_waitcnt vmcnt(0)" ::: "memory");
    __builtin_amdgcn_s_barrier();
    __builtin_amdgcn_sched_barrier(0);

    const char* kbase = (const char*)&Ks[cur][0];
    const char* vbase = (const char*)&VTs[cur][0];

    f32x16 sc0 = {}, sc1 = {};
#pragma unroll
    for (int dstep = 0; dstep < 4; ++dstep) {
      const int colb = (dstep * 32 + hi * 16);
      bf16x8 kf0 = *(const bf16x8*)(kbase + (size_t)q5 * 128 + (colb ^ (l7 << 4)));
      bf16x8 kf1 = *(const bf16x8*)(kbase + (size_t)(32 + q5) * 128 + (colb ^ (l7 << 4)));
      sc0 = __builtin_amdgcn_mfma_f32_32x32x16_bf16(kf0, qf[dstep], sc0, 0, 0, 0);
      sc1 = __builtin_amdgcn_mfma_f32_32x32x16_bf16(kf1, qf[dstep], sc1, 0, 0, 0);
    }
    if (ch == 15) {   // mask s >= 1000 (chunk 15, tile 1, regs r>=4)
#pragma unroll
      for (int r = 4; r < 16; ++r) sc1[r] = -3.0e38f;
    }

    float mi = sc0[0];
#pragma unroll
    for (int r = 1; r < 16; ++r) mi = fmaxf(mi, sc0[r]);
#pragma unroll
    for (int r = 0; r < 16; ++r) mi = fmaxf(mi, sc1[r]);
    float cm = fmaxf(mi, __shfl_xor(mi, 32, 64));

    if (__any(cm > m_run + 8.0f)) {        // defer-max (T13)
      float mn = fmaxf(m_run, cm);
      float fsc = exp2_fast(m_run - mn);
      m_run = mn;
      l_part *= fsc;
#pragma unroll
      for (int r = 0; r < 16; ++r) { oa0[r] *= fsc; oa1[r] *= fsc; }
    }

#pragma unroll
    for (int r = 0; r < 16; ++r) {
      float p0 = exp2_fast(sc0[r] - m_run); l_part += p0; sc0[r] = p0;
      float p1 = exp2_fast(sc1[r] - m_run); l_part += p1; sc1[r] = p1;
    }

#pragma unroll
    for (int st = 0; st < 2; ++st) {
#pragma unroll
      for (int ks = 0; ks < 2; ++ks) {
        float pv0, pv1, pv2, pv3, pv4, pv5, pv6, pv7;
        if (st == 0) {
          if (ks == 0) { pv0=sc0[0];pv1=sc0[1];pv2=sc0[2];pv3=sc0[3];pv4=sc0[4];pv5=sc0[5];pv6=sc0[6];pv7=sc0[7]; }
          else         { pv0=sc0[8];pv1=sc0[9];pv2=sc0[10];pv3=sc0[11];pv4=sc0[12];pv5=sc0[13];pv6=sc0[14];pv7=sc0[15]; }
        } else {
          if (ks == 0) { pv0=sc1[0];pv1=sc1[1];pv2=sc1[2];pv3=sc1[3];pv4=sc1[4];pv5=sc1[5];pv6=sc1[6];pv7=sc1[7]; }
          else         { pv0=sc1[8];pv1=sc1[9];pv2=sc1[10];pv3=sc1[11];pv4=sc1[12];pv5=sc1[13];pv6=sc1[14];pv7=sc1[15]; }
        }
        uint32_t a = pk_bf16(pv0, pv1), b = pk_bf16(pv2, pv3);
        uint32_t c = pk_bf16(pv4, pv5), d = pk_bf16(pv6, pv7);
        uint32_t sa = (uint32_t)__shfl_xor((int)a, 32, 64);
        uint32_t sb = (uint32_t)__shfl_xor((int)b, 32, 64);
        uint32_t sc_ = (uint32_t)__shfl_xor((int)c, 32, 64);
        uint32_t sd = (uint32_t)__shfl_xor((int)d, 32, 64);
        u32x4 jw;
        jw[0] = hi ? sc_ : a;
        jw[1] = hi ? sd  : b;
        jw[2] = hi ? c   : sa;
        jw[3] = hi ? d   : sb;
        bf16x8 pB = __builtin_bit_cast(bf16x8, jw);
        const int colb = (st * 64 + ks * 32 + hi * 16);
#pragma unroll
        for (int dt = 0; dt < 2; ++dt) {
          bf16x8 vtf = *(const bf16x8*)(vbase + (size_t)(dt * 32 + q5) * 128 + (colb ^ (l7 << 4)));
          if (dt == 0) oa0 = __builtin_amdgcn_mfma_f32_32x32x16_bf16(vtf, pB, oa0, 0, 0, 0);
          else         oa1 = __builtin_amdgcn_mfma_f32_32x32x16_bf16(vtf, pB, oa1, 0, 0, 0);
        }
      }
    }

    if (ch + 2 < 16) STAGE(ch + 2, (ch + 2) % 3);   // after barrier: buf (ch-1)%3 is free
  }

  float ool = 1.0f / (l_part + __shfl_xor(l_part, 32, 64));
  u16* obase = O + (size_t)qrow * DM + h * 64;
#pragma unroll
  for (int dt = 0; dt < 2; ++dt) {
#pragma unroll
    for (int g = 0; g < 4; ++g) {
      float v0, v1, v2, v3;
      if (dt == 0) { v0 = oa0[4*g]; v1 = oa0[4*g+1]; v2 = oa0[4*g+2]; v3 = oa0[4*g+3]; }
      else         { v0 = oa1[4*g]; v1 = oa1[4*g+1]; v2 = oa1[4*g+2]; v3 = oa1[4*g+3]; }
      u32x2 st2;
      st2[0] = pk_bf16(v0 * ool, v1 * ool);
      st2[1] = pk_bf16(v2 * ool, v3 * ool);
      *(u32x2*)(obase + dt * 32 + g * 8 + hi * 4) = st2;
    }
  }
}

// ---------------- host ----------------
extern "C" void kernel_launch(void* const* d_in, const int* in_sizes, int n_in,
                              void* d_out, int out_size, void* d_ws, size_t ws_size,
                              hipStream_t stream) {
  (void)in_sizes; (void)n_in; (void)out_size; (void)ws_size;
  const float* target = (const float*)d_in[0];
  const float* source = (const float*)d_in[1];
  const float* value  = (const float*)d_in[2];
  const float* Wq = (const float*)d_in[3];
  const float* bq = (const float*)d_in[4];
  const float* Wk = (const float*)d_in[5];
  const float* bk = (const float*)d_in[6];
  const float* Wv = (const float*)d_in[7];
  const float* bv = (const float*)d_in[8];
  const float* Wo = (const float*)d_in[9];
  const float* bo = (const float*)d_in[10];
  float* out = (float*)d_out;

  char* ws = (char*)d_ws;
  size_t off = 0;
  auto carve = [&](size_t bytes) { void* p = ws + off; off += (bytes + 255) & ~(size_t)255; return p; };
  u16* Xb  = (u16*)carve(8192ull * 768 * 2);
  u16* Sb  = (u16*)carve(1024ull * 4096 * 2);
  u16* Vbi = (u16*)carve(1024ull * 4096 * 2);
  u16* WqT = (u16*)carve(768ull * 768 * 2);
  u16* WkT = (u16*)carve(768ull * 4096 * 2);
  u16* WvT = (u16*)carve(768ull * 4096 * 2);
  u16* WoT = (u16*)carve(4096ull * 768 * 2);
  u16* Qb  = (u16*)carve(8192ull * 768 * 2);
  u16* Kp  = (u16*)carve(1024ull * 768 * 2);
  u16* VTp = (u16*)carve(768ull * 1024 * 2);
  u16* Ob  = (u16*)carve(8192ull * 768 * 2);

  const float SCL = 0.18033688011112042f;   // (1/8) * log2(e): exp2-domain scores

  // one launch: converts + all weight transposes (independent, memory-bound)
  preprocess_all<<<12864, 256, 0, stream>>>(target, Xb, source, Sb, value, Vbi,
                                            Wq, WqT, Wk, WkT, Wv, WvT, Wo, WoT);

  // K/V projection: split-K partials into d_out (scratch; overwritten by O-proj)
  gemm_kv_splitk_p<<<dim3(6, 8, 8), 256, 0, stream>>>(Sb, Vbi, WkT, WvT, out);
  kv_reduce_all<<<1536, 256, 0, stream>>>(out, bk, bv, Kp, VTp);

  // Q projection with exp2-domain scale folded in
  gemm_bt_128p<u16><<<dim3(6, 64), 256, 0, stream>>>(Xb, WqT, bq, Qb, 768, 768, SCL);

  attn_flash<<<dim3(64, 12), 256, 0, stream>>>(Qb, Kp, VTp, Ob);

  // output projection -> fp32 d_out (256^2 fine-phase kernel)
  gemm_bt_256p<<<dim3(16, 32), 512, 0, stream>>>(Ob, WoT, bo, out, 4096, 768);
}

// Round 17
// 186.635 us; speedup vs baseline: 1.2163x; 1.0213x over previous
//
#include <hip/hip_runtime.h>
#include <cstdint>
#include <type_traits>

// ReprogrammingLayer on MI355X (gfx950), round 17:
//  - Q-projection and split-K K/V projection fused into qkv_proj_fused (768 blocks,
//    identical 128p structure; fills the 2-block/CU capacity, removes a launch gap).
//  - everything else identical to round 16 (190.6 us). 5 launches total.

typedef unsigned short u16;
typedef __attribute__((ext_vector_type(8))) short bf16x8;    // 8 bf16 = 4 VGPR (MFMA A/B frag)
typedef __attribute__((ext_vector_type(4))) float f32x4;     // 16x16 MFMA C/D frag
typedef __attribute__((ext_vector_type(16))) float f32x16;   // 32x32 MFMA C/D frag
typedef __attribute__((ext_vector_type(4))) float fvec4;
typedef __attribute__((ext_vector_type(4))) unsigned short u16x4;
typedef __attribute__((ext_vector_type(4))) unsigned int u32x4;
typedef __attribute__((ext_vector_type(2))) unsigned int u32x2;

using gld_src_t = const __attribute__((address_space(1))) void*;
using gld_dst_t = __attribute__((address_space(3))) void*;

static __device__ __forceinline__ u16 bf16_rne(float f) {
  uint32_t u = __builtin_bit_cast(uint32_t, f);
  u += 0x7fffu + ((u >> 16) & 1u);          // round-to-nearest-even
  return (u16)(u >> 16);
}

static __device__ __forceinline__ float exp2_fast(float x) {
  float r; asm("v_exp_f32 %0, %1" : "=v"(r) : "v"(x)); return r;   // HW exp2
}

static __device__ __forceinline__ uint32_t pk_bf16(float a, float b) {
  return (uint32_t)bf16_rne(a) | ((uint32_t)bf16_rne(b) << 16);   // a -> low, b -> high
}

// ---------------- fused preprocessing: converts + all 4 weight transposes --------------
__global__ void preprocess_all(
    const float* __restrict__ target, u16* __restrict__ Xb,
    const float* __restrict__ source, u16* __restrict__ Sb,
    const float* __restrict__ value,  u16* __restrict__ Vbi,
    const float* __restrict__ Wq, u16* __restrict__ WqT,
    const float* __restrict__ Wk, u16* __restrict__ WkT,
    const float* __restrict__ Wv, u16* __restrict__ WvT,
    const float* __restrict__ Wo, u16* __restrict__ WoT) {
  __shared__ u16 tile[32][33];
  const int bi = blockIdx.x, tid = threadIdx.x;

  if (bi < 3072) {   // converts
    const int sel = bi >> 10;
    const int ib = bi & 1023;
    const float* in = sel == 0 ? target : (sel == 1 ? source : value);
    u16* out = sel == 0 ? Xb : (sel == 1 ? Sb : Vbi);
    const int C = sel == 0 ? 768 : 4096;
    const int validR = sel == 0 ? 8192 : 1000;
    const long n4 = sel == 0 ? (8192ll * 768 / 4) : (1024ll * 4096 / 4);
    const long stride = 1024ll * 256;
    for (long i = (long)ib * 256 + tid; i < n4; i += stride) {
      long e = i << 2;
      int r = (int)(e / C);
      u16x4 o;
      if (r < validR) {
        fvec4 v = *(const fvec4*)(in + e);
        o[0] = bf16_rne(v[0]); o[1] = bf16_rne(v[1]);
        o[2] = bf16_rne(v[2]); o[3] = bf16_rne(v[3]);
      } else {
        o[0] = 0; o[1] = 0; o[2] = 0; o[3] = 0;
      }
      *(u16x4*)(out + e) = o;
    }
    return;
  }

  int j = bi - 3072;
  const float* inv; u16* out; int R, C, bx, by;
  if (j < 576)        { inv = Wq; out = WqT; R = 768;  C = 768;  bx = j % 24;  by = j / 24; }
  else if (j < 3648)  { j -= 576;  inv = Wk; out = WkT; R = 4096; C = 768; bx = j % 24; by = j / 24; }
  else if (j < 6720)  { j -= 3648; inv = Wv; out = WvT; R = 4096; C = 768; bx = j % 24; by = j / 24; }
  else                { j -= 6720; inv = Wo; out = WoT; R = 768;  C = 4096; bx = j % 128; by = j / 128; }
  const int bc = bx * 32, br = by * 32;
  const int tx = tid & 31, ty = tid >> 5;
#pragma unroll
  for (int i = 0; i < 4; ++i) {
    int r = br + ty + i * 8, c = bc + tx;
    u16 bits = 0;
    if (r < R && c < C) bits = bf16_rne(inv[(size_t)r * C + c]);
    tile[ty + i * 8][tx] = bits;
  }
  __syncthreads();
#pragma unroll
  for (int i = 0; i < 4; ++i) {
    int orow = bc + ty + i * 8, oc = br + tx;
    if (orow < C && oc < R) out[(size_t)orow * R + oc] = tile[tx][ty + i * 8];
  }
}

// ---------------- fused Q-proj + split-K K/V proj (128p structure) ---------------------
// 768 blocks: bi<384 -> splitk (z=bi/48: {K,V}x4 kchunks; partials fp32 -> part);
//             bi>=384 -> Q-proj (XCD-swizzled, bf16 (acc+bq)*SCL -> Qb).
__global__ __launch_bounds__(256, 2) void qkv_proj_fused(
    const u16* __restrict__ Xb, const u16* __restrict__ Sb, const u16* __restrict__ Vbi,
    const u16* __restrict__ WqT, const u16* __restrict__ WkT, const u16* __restrict__ WvT,
    const float* __restrict__ bq, float* __restrict__ part, u16* __restrict__ Qb,
    float scl) {
  __shared__ u16 As[2][128 * 64];
  __shared__ u16 Bs[2][128 * 64];

  const int tid = threadIdx.x, lane = tid & 63, w = tid >> 6;
  const int lr = lane & 15, lg = lane >> 4;
  const int wr = (w >> 1) * 64, wc = (w & 1) * 64;

  const int bi = blockIdx.x;
  const bool isQ = bi >= 384;
  const u16 *A, *B;
  int Kst, nk, kofs, bm, bn;
  float* Cf = nullptr;
  if (!isQ) {
    const int z = bi / 48, rem = bi % 48;
    bm = (rem / 6) * 128; bn = (rem % 6) * 128;
    A = (z >> 2) ? Vbi : Sb;
    B = (z >> 2) ? WvT : WkT;
    Cf = part + (size_t)z * 786432;
    kofs = (z & 3) * 1024; Kst = 4096; nk = 16;
  } else {
    const int j = bi - 384;
    const int swz = (j & 7) * 48 + (j >> 3);   // bijective XCD swizzle (384 % 8 == 0)
    bm = (swz / 6) * 128; bn = (swz % 6) * 128;
    A = Xb; B = WqT; kofs = 0; Kst = 768; nk = 12;
  }

  f32x4 acc[4][4] = {};

  auto STAGE = [&](int t, int buf) {
#pragma unroll
    for (int it = 0; it < 4; ++it) {
      const int s = it * 256 + tid;
      const int r = s >> 3;
      const int cg = (s & 7) ^ (r & 7);
      const int ldsb = (it * 256 + w * 64) * 16;
      __builtin_amdgcn_global_load_lds(
          (gld_src_t)(const void*)(A + (size_t)(bm + r) * Kst + kofs + t * 64 + cg * 8),
          (gld_dst_t)((char*)&As[buf][0] + ldsb), 16, 0, 0);
      __builtin_amdgcn_global_load_lds(
          (gld_src_t)(const void*)(B + (size_t)(bn + r) * Kst + kofs + t * 64 + cg * 8),
          (gld_dst_t)((char*)&Bs[buf][0] + ldsb), 16, 0, 0);
    }
  };

  auto LDF = [&](const u16* base, int R, int CB) {
    return *(const bf16x8*)((const char*)base + (size_t)R * 128 + (CB ^ ((R & 7) << 4)));
  };

  STAGE(0, 0);

  for (int t = 0; t < nk; ++t) {
    const int cur = t & 1;
    if (t + 1 < nk) {
      STAGE(t + 1, cur ^ 1);
      asm volatile("s_waitcnt vmcnt(8)" ::: "memory");
    } else {
      asm volatile("s_waitcnt vmcnt(0)" ::: "memory");
    }
    __builtin_amdgcn_s_barrier();
    __builtin_amdgcn_sched_barrier(0);

    const u16* as = &As[cur][0];
    const u16* bs = &Bs[cur][0];

    bf16x8 af[4][2], bfr[4][2];
#pragma unroll
    for (int m = 0; m < 4; ++m)
#pragma unroll
      for (int kk = 0; kk < 2; ++kk)
        af[m][kk] = LDF(as, wr + m * 16 + lr, kk * 64 + lg * 16);
#pragma unroll
    for (int n = 0; n < 4; ++n)
#pragma unroll
      for (int kk = 0; kk < 2; ++kk)
        bfr[n][kk] = LDF(bs, wc + n * 16 + lr, kk * 64 + lg * 16);

    __builtin_amdgcn_s_setprio(1);
#pragma unroll
    for (int kk = 0; kk < 2; ++kk)
#pragma unroll
      for (int m = 0; m < 4; ++m)
#pragma unroll
        for (int n = 0; n < 4; ++n)
          acc[m][n] = __builtin_amdgcn_mfma_f32_16x16x32_bf16(
              af[m][kk], bfr[n][kk], acc[m][n], 0, 0, 0);
    __builtin_amdgcn_s_setprio(0);

    __builtin_amdgcn_sched_barrier(0);
    __builtin_amdgcn_s_barrier();
  }

  if (isQ) {
#pragma unroll
    for (int n = 0; n < 4; ++n) {
      const int col = bn + wc + n * 16 + lr;
      const float bv = bq[col];
#pragma unroll
      for (int m = 0; m < 4; ++m) {
        const int row0 = bm + wr + m * 16 + lg * 4;
#pragma unroll
        for (int r = 0; r < 4; ++r)
          Qb[(size_t)(row0 + r) * 768 + col] = bf16_rne((acc[m][n][r] + bv) * scl);
      }
    }
  } else {
#pragma unroll
    for (int n = 0; n < 4; ++n) {
      const int col = bn + wc + n * 16 + lr;
#pragma unroll
      for (int m = 0; m < 4; ++m) {
        const int row0 = bm + wr + m * 16 + lg * 4;
#pragma unroll
        for (int r = 0; r < 4; ++r)
          Cf[(size_t)(row0 + r) * 768 + col] = acc[m][n][r];
      }
    }
  }
}

// ---------------- fused reduces: blocks [0,768) K-reduce; [768,1536) V-reduce+transpose
__global__ __launch_bounds__(256) void kv_reduce_all(const float* __restrict__ part,
                                                     const float* __restrict__ bk,
                                                     const float* __restrict__ bv,
                                                     u16* __restrict__ Kp,
                                                     u16* __restrict__ VTp) {
  __shared__ u16 tile[32][33];
  const int bi = blockIdx.x;
  if (bi < 768) {
    const long e = ((long)bi * 256 + threadIdx.x) * 4;
    const float* p0 = part + e;
    fvec4 s = *(const fvec4*)p0;
    s += *(const fvec4*)(p0 + 786432);
    s += *(const fvec4*)(p0 + 2 * 786432);
    s += *(const fvec4*)(p0 + 3 * 786432);
    int col = (int)(e % 768);
    s += *(const fvec4*)(bk + col);
    u16x4 o;
    o[0] = bf16_rne(s[0]); o[1] = bf16_rne(s[1]); o[2] = bf16_rne(s[2]); o[3] = bf16_rne(s[3]);
    *(u16x4*)(Kp + e) = o;
    return;
  }
  const int j = bi - 768;
  const float* pv = part + 4ull * 786432;
  const int c0 = (j % 24) * 32, r0 = (j / 24) * 32;
  const int tx = threadIdx.x & 31, ty = threadIdx.x >> 5;
#pragma unroll
  for (int i = 0; i < 4; ++i) {
    const int r = r0 + ty + i * 8, c = c0 + tx;
    const size_t idx = (size_t)r * 768 + c;
    float s = pv[idx] + pv[idx + 786432] + pv[idx + 2 * 786432] + pv[idx + 3 * 786432]
            + bv[c];
    tile[ty + i * 8][tx] = bf16_rne(s);
  }
  __syncthreads();
#pragma unroll
  for (int i = 0; i < 4; ++i) {
    const int vr = c0 + ty + i * 8;
    const int vc = r0 + tx;
    VTp[(size_t)vr * 1024 + vc] = tile[tx][ty + i * 8];
  }
}

// ---------------- 256x256-tile BK=32 fine-phase GEMM (O-projection; round-11 proven) ----
__global__ __launch_bounds__(512, 2) void gemm_bt_256p(
    const u16* __restrict__ A, const u16* __restrict__ B,
    const float* __restrict__ bias, float* __restrict__ C,
    int N, int K) {
  __shared__ u16 As[4][128 * 64];   // 4 x 16 KB
  __shared__ u16 Bs[4][128 * 64];   // 4 x 16 KB

  const int tid = threadIdx.x, lane = tid & 63, w = tid >> 6;
  const int lr = lane & 15, lg = lane >> 4;
  const int wr = w >> 2, wcol = w & 3;

  const int nbx = N >> 8;
  const int bid = blockIdx.y * gridDim.x + blockIdx.x;
  const int cpx = (gridDim.x * gridDim.y) >> 3;
  const int swz = (bid & 7) * cpx + (bid >> 3);
  const int bm = (swz / nbx) * 256, bn = (swz % nbx) * 256;

  f32x4 acc[8][4] = {};

  auto STAGE_UNIT = [&](int t, int buf, int mat) {
#pragma unroll
    for (int it = 0; it < 2; ++it) {
      const int s = it * 512 + tid;
      const int rp = s >> 3;
      const int cl = (s & 7) ^ (rp & 7);
      const int gr = (cl >> 2) * 128 + rp;
      const int gc = cl & 3;
      const int ldsb = (it * 512 + w * 64) * 16;
      const u16* src = (mat ? B : A) + (size_t)((mat ? bn : bm) + gr) * K + t * 32 + gc * 8;
      __builtin_amdgcn_global_load_lds((gld_src_t)(const void*)src,
          (gld_dst_t)((char*)(mat ? &Bs[buf][0] : &As[buf][0]) + ldsb), 16, 0, 0);
    }
  };

  auto LDF = [&](const u16* base, int gr, int klg) {
    const int byte = (gr & 127) * 128 + (((((gr >> 7) * 4 + klg) << 4)) ^ ((gr & 7) << 4));
    return *(const bf16x8*)((const char*)base + byte);
  };

  STAGE_UNIT(0, 0, 0); STAGE_UNIT(0, 0, 1);
  STAGE_UNIT(1, 1, 0); STAGE_UNIT(1, 1, 1);
  asm volatile("s_waitcnt vmcnt(4)" ::: "memory");
  __builtin_amdgcn_s_barrier();
  __builtin_amdgcn_sched_barrier(0);

  const int nk = K >> 5;   // 24
  bf16x8 bfr[4];
  for (int t = 0; t < nk; ++t) {
    const int cur = t & 3;
    const u16* as = &As[cur][0];
    const u16* bs = &Bs[cur][0];
#pragma unroll
    for (int p = 0; p < 2; ++p) {
      bf16x8 af[4];
#pragma unroll
      for (int m = 0; m < 4; ++m)
        af[m] = LDF(as, wr * 128 + (p * 4 + m) * 16 + lr, lg);
      if (p == 0) {
#pragma unroll
        for (int n = 0; n < 4; ++n)
          bfr[n] = LDF(bs, wcol * 64 + n * 16 + lr, lg);
      }
      if (t + 2 < nk) STAGE_UNIT(t + 2, (t + 2) & 3, p);
      if (p == 1) {
        if (t + 2 < nk)      asm volatile("s_waitcnt vmcnt(4)" ::: "memory");
        else if (t + 1 < nk) asm volatile("s_waitcnt vmcnt(0)" ::: "memory");
      }
      __builtin_amdgcn_s_barrier();
      __builtin_amdgcn_sched_barrier(0);
      __builtin_amdgcn_s_setprio(1);
#pragma unroll
      for (int m = 0; m < 4; ++m)
#pragma unroll
        for (int n = 0; n < 4; ++n)
          acc[p * 4 + m][n] = __builtin_amdgcn_mfma_f32_16x16x32_bf16(
              af[m], bfr[n], acc[p * 4 + m][n], 0, 0, 0);
      __builtin_amdgcn_s_setprio(0);
      __builtin_amdgcn_sched_barrier(0);
    }
  }

  float bv[4];
#pragma unroll
  for (int nf = 0; nf < 4; ++nf) bv[nf] = bias[bn + wcol * 64 + nf * 16 + lr];
#pragma unroll
  for (int mf = 0; mf < 8; ++mf) {
    const int row0 = bm + wr * 128 + mf * 16 + lg * 4;
#pragma unroll
    for (int nf = 0; nf < 4; ++nf) {
      const int col = bn + wcol * 64 + nf * 16 + lr;
#pragma unroll
      for (int r = 0; r < 4; ++r)
        C[(size_t)(row0 + r) * N + col] = acc[mf][nf][r] + bv[nf];
    }
  }
}

// ---------------- swapped-QK^T flash attention (round-14 exact: 3-ring, 1 barrier) -----
__global__ __launch_bounds__(256, 3) void attn_flash(
    const u16* __restrict__ Q,   // [8192, 768] bf16, pre-scaled
    const u16* __restrict__ Kb,  // [1024, 768] bf16 (rows >= 1000 are zero-padded)
    const u16* __restrict__ VT,  // [768, 1024] bf16
    u16* __restrict__ O) {       // [8192, 768] bf16
  constexpr int DM = 768, SPAD = 1024;
  __shared__ u16 Ks[3][64 * 64];    // 3 x 8 KB
  __shared__ u16 VTs[3][64 * 64];   // 3 x 8 KB

  const int tid = threadIdx.x, w = tid >> 6, lane = tid & 63;
  const int q5 = lane & 31, hi = lane >> 5, l7 = lane & 7;
  const int h = blockIdx.y;
  const int qrow = blockIdx.x * 128 + w * 32 + q5;

  bf16x8 qf[4];
#pragma unroll
  for (int dstep = 0; dstep < 4; ++dstep)
    qf[dstep] = *(const bf16x8*)(Q + (size_t)qrow * DM + h * 64 + dstep * 16 + hi * 8);

  auto STAGE = [&](int ch, int buf) {
#pragma unroll
    for (int it = 0; it < 2; ++it) {
      int slot = it * 256 + w * 64 + lane;
      int row = slot >> 3;
      int cg = (slot & 7) ^ (row & 7);
      __builtin_amdgcn_global_load_lds(
          (gld_src_t)(const void*)(Kb + (size_t)(ch * 64 + row) * DM + h * 64 + cg * 8),
          (gld_dst_t)(&Ks[buf][(size_t)(it * 256 + w * 64) * 8]), 16, 0, 0);
      __builtin_amdgcn_global_load_lds(
          (gld_src_t)(const void*)(VT + (size_t)(h * 64 + row) * SPAD + ch * 64 + cg * 8),
          (gld_dst_t)(&VTs[buf][(size_t)(it * 256 + w * 64) * 8]), 16, 0, 0);
    }
  };

  STAGE(0, 0);
  STAGE(1, 1);

  float m_run = -3.0e38f, l_part = 0.0f;
  f32x16 oa0 = {}, oa1 = {};

  for (int ch = 0; ch < 16; ++ch) {
    const int cur = ch % 3;
    if (ch < 15) asm volatile("s_waitcnt vmcnt(4)" ::: "memory");   // stage(ch) landed
    else         asm volatile("s_waitcnt vmcnt(0)" ::: "memory");
    __builtin_amdgcn_s_barrier();
    __builtin_amdgcn_sched_barrier(0);

    const char* kbase = (const char*)&Ks[cur][0];
    const char* vbase = (const char*)&VTs[cur][0];

    f32x16 sc0 = {}, sc1 = {};
#pragma unroll
    for (int dstep = 0; dstep < 4; ++dstep) {
      const int colb = (dstep * 32 + hi * 16);
      bf16x8 kf0 = *(const bf16x8*)(kbase + (size_t)q5 * 128 + (colb ^ (l7 << 4)));
      bf16x8 kf1 = *(const bf16x8*)(kbase + (size_t)(32 + q5) * 128 + (colb ^ (l7 << 4)));
      sc0 = __builtin_amdgcn_mfma_f32_32x32x16_bf16(kf0, qf[dstep], sc0, 0, 0, 0);
      sc1 = __builtin_amdgcn_mfma_f32_32x32x16_bf16(kf1, qf[dstep], sc1, 0, 0, 0);
    }
    if (ch == 15) {   // mask s >= 1000 (chunk 15, tile 1, regs r>=4)
#pragma unroll
      for (int r = 4; r < 16; ++r) sc1[r] = -3.0e38f;
    }

    float mi = sc0[0];
#pragma unroll
    for (int r = 1; r < 16; ++r) mi = fmaxf(mi, sc0[r]);
#pragma unroll
    for (int r = 0; r < 16; ++r) mi = fmaxf(mi, sc1[r]);
    float cm = fmaxf(mi, __shfl_xor(mi, 32, 64));

    if (__any(cm > m_run + 8.0f)) {        // defer-max (T13)
      float mn = fmaxf(m_run, cm);
      float fsc = exp2_fast(m_run - mn);
      m_run = mn;
      l_part *= fsc;
#pragma unroll
      for (int r = 0; r < 16; ++r) { oa0[r] *= fsc; oa1[r] *= fsc; }
    }

#pragma unroll
    for (int r = 0; r < 16; ++r) {
      float p0 = exp2_fast(sc0[r] - m_run); l_part += p0; sc0[r] = p0;
      float p1 = exp2_fast(sc1[r] - m_run); l_part += p1; sc1[r] = p1;
    }

#pragma unroll
    for (int st = 0; st < 2; ++st) {
#pragma unroll
      for (int ks = 0; ks < 2; ++ks) {
        float pv0, pv1, pv2, pv3, pv4, pv5, pv6, pv7;
        if (st == 0) {
          if (ks == 0) { pv0=sc0[0];pv1=sc0[1];pv2=sc0[2];pv3=sc0[3];pv4=sc0[4];pv5=sc0[5];pv6=sc0[6];pv7=sc0[7]; }
          else         { pv0=sc0[8];pv1=sc0[9];pv2=sc0[10];pv3=sc0[11];pv4=sc0[12];pv5=sc0[13];pv6=sc0[14];pv7=sc0[15]; }
        } else {
          if (ks == 0) { pv0=sc1[0];pv1=sc1[1];pv2=sc1[2];pv3=sc1[3];pv4=sc1[4];pv5=sc1[5];pv6=sc1[6];pv7=sc1[7]; }
          else         { pv0=sc1[8];pv1=sc1[9];pv2=sc1[10];pv3=sc1[11];pv4=sc1[12];pv5=sc1[13];pv6=sc1[14];pv7=sc1[15]; }
        }
        uint32_t a = pk_bf16(pv0, pv1), b = pk_bf16(pv2, pv3);
        uint32_t c = pk_bf16(pv4, pv5), d = pk_bf16(pv6, pv7);
        uint32_t sa = (uint32_t)__shfl_xor((int)a, 32, 64);
        uint32_t sb = (uint32_t)__shfl_xor((int)b, 32, 64);
        uint32_t sc_ = (uint32_t)__shfl_xor((int)c, 32, 64);
        uint32_t sd = (uint32_t)__shfl_xor((int)d, 32, 64);
        u32x4 jw;
        jw[0] = hi ? sc_ : a;
        jw[1] = hi ? sd  : b;
        jw[2] = hi ? c   : sa;
        jw[3] = hi ? d   : sb;
        bf16x8 pB = __builtin_bit_cast(bf16x8, jw);
        const int colb = (st * 64 + ks * 32 + hi * 16);
#pragma unroll
        for (int dt = 0; dt < 2; ++dt) {
          bf16x8 vtf = *(const bf16x8*)(vbase + (size_t)(dt * 32 + q5) * 128 + (colb ^ (l7 << 4)));
          if (dt == 0) oa0 = __builtin_amdgcn_mfma_f32_32x32x16_bf16(vtf, pB, oa0, 0, 0, 0);
          else         oa1 = __builtin_amdgcn_mfma_f32_32x32x16_bf16(vtf, pB, oa1, 0, 0, 0);
        }
      }
    }

    if (ch + 2 < 16) STAGE(ch + 2, (ch + 2) % 3);   // after barrier: buf (ch-1)%3 is free
  }

  float ool = 1.0f / (l_part + __shfl_xor(l_part, 32, 64));
  u16* obase = O + (size_t)qrow * DM + h * 64;
#pragma unroll
  for (int dt = 0; dt < 2; ++dt) {
#pragma unroll
    for (int g = 0; g < 4; ++g) {
      float v0, v1, v2, v3;
      if (dt == 0) { v0 = oa0[4*g]; v1 = oa0[4*g+1]; v2 = oa0[4*g+2]; v3 = oa0[4*g+3]; }
      else         { v0 = oa1[4*g]; v1 = oa1[4*g+1]; v2 = oa1[4*g+2]; v3 = oa1[4*g+3]; }
      u32x2 st2;
      st2[0] = pk_bf16(v0 * ool, v1 * ool);
      st2[1] = pk_bf16(v2 * ool, v3 * ool);
      *(u32x2*)(obase + dt * 32 + g * 8 + hi * 4) = st2;
    }
  }
}

// ---------------- host ----------------
extern "C" void kernel_launch(void* const* d_in, const int* in_sizes, int n_in,
                              void* d_out, int out_size, void* d_ws, size_t ws_size,
                              hipStream_t stream) {
  (void)in_sizes; (void)n_in; (void)out_size; (void)ws_size;
  const float* target = (const float*)d_in[0];
  const float* source = (const float*)d_in[1];
  const float* value  = (const float*)d_in[2];
  const float* Wq = (const float*)d_in[3];
  const float* bq = (const float*)d_in[4];
  const float* Wk = (const float*)d_in[5];
  const float* bk = (const float*)d_in[6];
  const float* Wv = (const float*)d_in[7];
  const float* bv = (const float*)d_in[8];
  const float* Wo = (const float*)d_in[9];
  const float* bo = (const float*)d_in[10];
  float* out = (float*)d_out;

  char* ws = (char*)d_ws;
  size_t off = 0;
  auto carve = [&](size_t bytes) { void* p = ws + off; off += (bytes + 255) & ~(size_t)255; return p; };
  u16* Xb  = (u16*)carve(8192ull * 768 * 2);
  u16* Sb  = (u16*)carve(1024ull * 4096 * 2);
  u16* Vbi = (u16*)carve(1024ull * 4096 * 2);
  u16* WqT = (u16*)carve(768ull * 768 * 2);
  u16* WkT = (u16*)carve(768ull * 4096 * 2);
  u16* WvT = (u16*)carve(768ull * 4096 * 2);
  u16* WoT = (u16*)carve(4096ull * 768 * 2);
  u16* Qb  = (u16*)carve(8192ull * 768 * 2);
  u16* Kp  = (u16*)carve(1024ull * 768 * 2);
  u16* VTp = (u16*)carve(768ull * 1024 * 2);
  u16* Ob  = (u16*)carve(8192ull * 768 * 2);

  const float SCL = 0.18033688011112042f;   // (1/8) * log2(e): exp2-domain scores

  preprocess_all<<<12864, 256, 0, stream>>>(target, Xb, source, Sb, value, Vbi,
                                            Wq, WqT, Wk, WkT, Wv, WvT, Wo, WoT);

  // fused Q-projection + split-K K/V projection (partials into d_out scratch)
  qkv_proj_fused<<<768, 256, 0, stream>>>(Xb, Sb, Vbi, WqT, WkT, WvT, bq, out, Qb, SCL);

  kv_reduce_all<<<1536, 256, 0, stream>>>(out, bk, bv, Kp, VTp);

  attn_flash<<<dim3(64, 12), 256, 0, stream>>>(Qb, Kp, VTp, Ob);

  gemm_bt_256p<<<dim3(16, 32), 512, 0, stream>>>(Ob, WoT, bo, out, 4096, 768);
}

// Round 18
// 186.562 us; speedup vs baseline: 1.2168x; 1.0004x over previous
//
#include <hip/hip_runtime.h>
#include <cstdint>
#include <type_traits>

// ReprogrammingLayer on MI355X (gfx950), round 18:
//  - single change vs round 17 (186.6 us): gemm_bt_256p prefetch depth 1 tile -> 2 tiles
//    in flight (stage t+3 during tile t; vmcnt(8) steady-state, taper 8->4->0; prologue
//    stages tiles 0,1,2). Race-free: buf (t+3)&3 == (t-1)&3, readers done pre-barrier.

typedef unsigned short u16;
typedef __attribute__((ext_vector_type(8))) short bf16x8;    // 8 bf16 = 4 VGPR (MFMA A/B frag)
typedef __attribute__((ext_vector_type(4))) float f32x4;     // 16x16 MFMA C/D frag
typedef __attribute__((ext_vector_type(16))) float f32x16;   // 32x32 MFMA C/D frag
typedef __attribute__((ext_vector_type(4))) float fvec4;
typedef __attribute__((ext_vector_type(4))) unsigned short u16x4;
typedef __attribute__((ext_vector_type(4))) unsigned int u32x4;
typedef __attribute__((ext_vector_type(2))) unsigned int u32x2;

using gld_src_t = const __attribute__((address_space(1))) void*;
using gld_dst_t = __attribute__((address_space(3))) void*;

static __device__ __forceinline__ u16 bf16_rne(float f) {
  uint32_t u = __builtin_bit_cast(uint32_t, f);
  u += 0x7fffu + ((u >> 16) & 1u);          // round-to-nearest-even
  return (u16)(u >> 16);
}

static __device__ __forceinline__ float exp2_fast(float x) {
  float r; asm("v_exp_f32 %0, %1" : "=v"(r) : "v"(x)); return r;   // HW exp2
}

static __device__ __forceinline__ uint32_t pk_bf16(float a, float b) {
  return (uint32_t)bf16_rne(a) | ((uint32_t)bf16_rne(b) << 16);   // a -> low, b -> high
}

// ---------------- fused preprocessing: converts + all 4 weight transposes --------------
__global__ void preprocess_all(
    const float* __restrict__ target, u16* __restrict__ Xb,
    const float* __restrict__ source, u16* __restrict__ Sb,
    const float* __restrict__ value,  u16* __restrict__ Vbi,
    const float* __restrict__ Wq, u16* __restrict__ WqT,
    const float* __restrict__ Wk, u16* __restrict__ WkT,
    const float* __restrict__ Wv, u16* __restrict__ WvT,
    const float* __restrict__ Wo, u16* __restrict__ WoT) {
  __shared__ u16 tile[32][33];
  const int bi = blockIdx.x, tid = threadIdx.x;

  if (bi < 3072) {   // converts
    const int sel = bi >> 10;
    const int ib = bi & 1023;
    const float* in = sel == 0 ? target : (sel == 1 ? source : value);
    u16* out = sel == 0 ? Xb : (sel == 1 ? Sb : Vbi);
    const int C = sel == 0 ? 768 : 4096;
    const int validR = sel == 0 ? 8192 : 1000;
    const long n4 = sel == 0 ? (8192ll * 768 / 4) : (1024ll * 4096 / 4);
    const long stride = 1024ll * 256;
    for (long i = (long)ib * 256 + tid; i < n4; i += stride) {
      long e = i << 2;
      int r = (int)(e / C);
      u16x4 o;
      if (r < validR) {
        fvec4 v = *(const fvec4*)(in + e);
        o[0] = bf16_rne(v[0]); o[1] = bf16_rne(v[1]);
        o[2] = bf16_rne(v[2]); o[3] = bf16_rne(v[3]);
      } else {
        o[0] = 0; o[1] = 0; o[2] = 0; o[3] = 0;
      }
      *(u16x4*)(out + e) = o;
    }
    return;
  }

  int j = bi - 3072;
  const float* inv; u16* out; int R, C, bx, by;
  if (j < 576)        { inv = Wq; out = WqT; R = 768;  C = 768;  bx = j % 24;  by = j / 24; }
  else if (j < 3648)  { j -= 576;  inv = Wk; out = WkT; R = 4096; C = 768; bx = j % 24; by = j / 24; }
  else if (j < 6720)  { j -= 3648; inv = Wv; out = WvT; R = 4096; C = 768; bx = j % 24; by = j / 24; }
  else                { j -= 6720; inv = Wo; out = WoT; R = 768;  C = 4096; bx = j % 128; by = j / 128; }
  const int bc = bx * 32, br = by * 32;
  const int tx = tid & 31, ty = tid >> 5;
#pragma unroll
  for (int i = 0; i < 4; ++i) {
    int r = br + ty + i * 8, c = bc + tx;
    u16 bits = 0;
    if (r < R && c < C) bits = bf16_rne(inv[(size_t)r * C + c]);
    tile[ty + i * 8][tx] = bits;
  }
  __syncthreads();
#pragma unroll
  for (int i = 0; i < 4; ++i) {
    int orow = bc + ty + i * 8, oc = br + tx;
    if (orow < C && oc < R) out[(size_t)orow * R + oc] = tile[tx][ty + i * 8];
  }
}

// ---------------- fused Q-proj + split-K K/V proj (128p structure) ---------------------
__global__ __launch_bounds__(256, 2) void qkv_proj_fused(
    const u16* __restrict__ Xb, const u16* __restrict__ Sb, const u16* __restrict__ Vbi,
    const u16* __restrict__ WqT, const u16* __restrict__ WkT, const u16* __restrict__ WvT,
    const float* __restrict__ bq, float* __restrict__ part, u16* __restrict__ Qb,
    float scl) {
  __shared__ u16 As[2][128 * 64];
  __shared__ u16 Bs[2][128 * 64];

  const int tid = threadIdx.x, lane = tid & 63, w = tid >> 6;
  const int lr = lane & 15, lg = lane >> 4;
  const int wr = (w >> 1) * 64, wc = (w & 1) * 64;

  const int bi = blockIdx.x;
  const bool isQ = bi >= 384;
  const u16 *A, *B;
  int Kst, nk, kofs, bm, bn;
  float* Cf = nullptr;
  if (!isQ) {
    const int z = bi / 48, rem = bi % 48;
    bm = (rem / 6) * 128; bn = (rem % 6) * 128;
    A = (z >> 2) ? Vbi : Sb;
    B = (z >> 2) ? WvT : WkT;
    Cf = part + (size_t)z * 786432;
    kofs = (z & 3) * 1024; Kst = 4096; nk = 16;
  } else {
    const int j = bi - 384;
    const int swz = (j & 7) * 48 + (j >> 3);
    bm = (swz / 6) * 128; bn = (swz % 6) * 128;
    A = Xb; B = WqT; kofs = 0; Kst = 768; nk = 12;
  }

  f32x4 acc[4][4] = {};

  auto STAGE = [&](int t, int buf) {
#pragma unroll
    for (int it = 0; it < 4; ++it) {
      const int s = it * 256 + tid;
      const int r = s >> 3;
      const int cg = (s & 7) ^ (r & 7);
      const int ldsb = (it * 256 + w * 64) * 16;
      __builtin_amdgcn_global_load_lds(
          (gld_src_t)(const void*)(A + (size_t)(bm + r) * Kst + kofs + t * 64 + cg * 8),
          (gld_dst_t)((char*)&As[buf][0] + ldsb), 16, 0, 0);
      __builtin_amdgcn_global_load_lds(
          (gld_src_t)(const void*)(B + (size_t)(bn + r) * Kst + kofs + t * 64 + cg * 8),
          (gld_dst_t)((char*)&Bs[buf][0] + ldsb), 16, 0, 0);
    }
  };

  auto LDF = [&](const u16* base, int R, int CB) {
    return *(const bf16x8*)((const char*)base + (size_t)R * 128 + (CB ^ ((R & 7) << 4)));
  };

  STAGE(0, 0);

  for (int t = 0; t < nk; ++t) {
    const int cur = t & 1;
    if (t + 1 < nk) {
      STAGE(t + 1, cur ^ 1);
      asm volatile("s_waitcnt vmcnt(8)" ::: "memory");
    } else {
      asm volatile("s_waitcnt vmcnt(0)" ::: "memory");
    }
    __builtin_amdgcn_s_barrier();
    __builtin_amdgcn_sched_barrier(0);

    const u16* as = &As[cur][0];
    const u16* bs = &Bs[cur][0];

    bf16x8 af[4][2], bfr[4][2];
#pragma unroll
    for (int m = 0; m < 4; ++m)
#pragma unroll
      for (int kk = 0; kk < 2; ++kk)
        af[m][kk] = LDF(as, wr + m * 16 + lr, kk * 64 + lg * 16);
#pragma unroll
    for (int n = 0; n < 4; ++n)
#pragma unroll
      for (int kk = 0; kk < 2; ++kk)
        bfr[n][kk] = LDF(bs, wc + n * 16 + lr, kk * 64 + lg * 16);

    __builtin_amdgcn_s_setprio(1);
#pragma unroll
    for (int kk = 0; kk < 2; ++kk)
#pragma unroll
      for (int m = 0; m < 4; ++m)
#pragma unroll
        for (int n = 0; n < 4; ++n)
          acc[m][n] = __builtin_amdgcn_mfma_f32_16x16x32_bf16(
              af[m][kk], bfr[n][kk], acc[m][n], 0, 0, 0);
    __builtin_amdgcn_s_setprio(0);

    __builtin_amdgcn_sched_barrier(0);
    __builtin_amdgcn_s_barrier();
  }

  if (isQ) {
#pragma unroll
    for (int n = 0; n < 4; ++n) {
      const int col = bn + wc + n * 16 + lr;
      const float bv = bq[col];
#pragma unroll
      for (int m = 0; m < 4; ++m) {
        const int row0 = bm + wr + m * 16 + lg * 4;
#pragma unroll
        for (int r = 0; r < 4; ++r)
          Qb[(size_t)(row0 + r) * 768 + col] = bf16_rne((acc[m][n][r] + bv) * scl);
      }
    }
  } else {
#pragma unroll
    for (int n = 0; n < 4; ++n) {
      const int col = bn + wc + n * 16 + lr;
#pragma unroll
      for (int m = 0; m < 4; ++m) {
        const int row0 = bm + wr + m * 16 + lg * 4;
#pragma unroll
        for (int r = 0; r < 4; ++r)
          Cf[(size_t)(row0 + r) * 768 + col] = acc[m][n][r];
      }
    }
  }
}

// ---------------- fused reduces: blocks [0,768) K-reduce; [768,1536) V-reduce+transpose
__global__ __launch_bounds__(256) void kv_reduce_all(const float* __restrict__ part,
                                                     const float* __restrict__ bk,
                                                     const float* __restrict__ bv,
                                                     u16* __restrict__ Kp,
                                                     u16* __restrict__ VTp) {
  __shared__ u16 tile[32][33];
  const int bi = blockIdx.x;
  if (bi < 768) {
    const long e = ((long)bi * 256 + threadIdx.x) * 4;
    const float* p0 = part + e;
    fvec4 s = *(const fvec4*)p0;
    s += *(const fvec4*)(p0 + 786432);
    s += *(const fvec4*)(p0 + 2 * 786432);
    s += *(const fvec4*)(p0 + 3 * 786432);
    int col = (int)(e % 768);
    s += *(const fvec4*)(bk + col);
    u16x4 o;
    o[0] = bf16_rne(s[0]); o[1] = bf16_rne(s[1]); o[2] = bf16_rne(s[2]); o[3] = bf16_rne(s[3]);
    *(u16x4*)(Kp + e) = o;
    return;
  }
  const int j = bi - 768;
  const float* pv = part + 4ull * 786432;
  const int c0 = (j % 24) * 32, r0 = (j / 24) * 32;
  const int tx = threadIdx.x & 31, ty = threadIdx.x >> 5;
#pragma unroll
  for (int i = 0; i < 4; ++i) {
    const int r = r0 + ty + i * 8, c = c0 + tx;
    const size_t idx = (size_t)r * 768 + c;
    float s = pv[idx] + pv[idx + 786432] + pv[idx + 2 * 786432] + pv[idx + 3 * 786432]
            + bv[c];
    tile[ty + i * 8][tx] = bf16_rne(s);
  }
  __syncthreads();
#pragma unroll
  for (int i = 0; i < 4; ++i) {
    const int vr = c0 + ty + i * 8;
    const int vc = r0 + tx;
    VTp[(size_t)vr * 1024 + vc] = tile[tx][ty + i * 8];
  }
}

// ---------------- 256x256-tile BK=32 fine-phase GEMM, 3-deep prefetch (O-projection) ---
// Tile t lives in buf[t&3]; during tile t we stage tile t+3 into buf[(t+3)&3]=(t-1)&3
// (readers finished before the barrier every wave crossed entering tile t). Steady-state
// vmcnt(8): stage(t+2)+stage(t+3) in flight, stage(t+1) landed -> ~2 tiles of latency
// cover per stage. Prologue stages tiles 0,1,2.
__global__ __launch_bounds__(512, 2) void gemm_bt_256p(
    const u16* __restrict__ A, const u16* __restrict__ B,
    const float* __restrict__ bias, float* __restrict__ C,
    int N, int K) {
  __shared__ u16 As[4][128 * 64];   // 4 x 16 KB
  __shared__ u16 Bs[4][128 * 64];   // 4 x 16 KB

  const int tid = threadIdx.x, lane = tid & 63, w = tid >> 6;
  const int lr = lane & 15, lg = lane >> 4;
  const int wr = w >> 2, wcol = w & 3;

  const int nbx = N >> 8;
  const int bid = blockIdx.y * gridDim.x + blockIdx.x;
  const int cpx = (gridDim.x * gridDim.y) >> 3;
  const int swz = (bid & 7) * cpx + (bid >> 3);
  const int bm = (swz / nbx) * 256, bn = (swz % nbx) * 256;

  f32x4 acc[8][4] = {};

  auto STAGE_UNIT = [&](int t, int buf, int mat) {
#pragma unroll
    for (int it = 0; it < 2; ++it) {
      const int s = it * 512 + tid;
      const int rp = s >> 3;
      const int cl = (s & 7) ^ (rp & 7);
      const int gr = (cl >> 2) * 128 + rp;
      const int gc = cl & 3;
      const int ldsb = (it * 512 + w * 64) * 16;
      const u16* src = (mat ? B : A) + (size_t)((mat ? bn : bm) + gr) * K + t * 32 + gc * 8;
      __builtin_amdgcn_global_load_lds((gld_src_t)(const void*)src,
          (gld_dst_t)((char*)(mat ? &Bs[buf][0] : &As[buf][0]) + ldsb), 16, 0, 0);
    }
  };

  auto LDF = [&](const u16* base, int gr, int klg) {
    const int byte = (gr & 127) * 128 + (((((gr >> 7) * 4 + klg) << 4)) ^ ((gr & 7) << 4));
    return *(const bf16x8*)((const char*)base + byte);
  };

  // prologue: stage tiles 0,1,2; tile 0 landed when vmcnt <= 8 (tiles 1,2 in flight)
  STAGE_UNIT(0, 0, 0); STAGE_UNIT(0, 0, 1);
  STAGE_UNIT(1, 1, 0); STAGE_UNIT(1, 1, 1);
  STAGE_UNIT(2, 2, 0); STAGE_UNIT(2, 2, 1);
  asm volatile("s_waitcnt vmcnt(8)" ::: "memory");
  __builtin_amdgcn_s_barrier();
  __builtin_amdgcn_sched_barrier(0);

  const int nk = K >> 5;   // 24
  bf16x8 bfr[4];
  for (int t = 0; t < nk; ++t) {
    const int cur = t & 3;
    const u16* as = &As[cur][0];
    const u16* bs = &Bs[cur][0];
#pragma unroll
    for (int p = 0; p < 2; ++p) {
      bf16x8 af[4];
#pragma unroll
      for (int m = 0; m < 4; ++m)
        af[m] = LDF(as, wr * 128 + (p * 4 + m) * 16 + lr, lg);
      if (p == 0) {
#pragma unroll
        for (int n = 0; n < 4; ++n)
          bfr[n] = LDF(bs, wcol * 64 + n * 16 + lr, lg);
      }
      if (t + 3 < nk) STAGE_UNIT(t + 3, (t + 3) & 3, p);
      if (p == 1) {
        // need stage(t+1) landed; outstanding allowed = stage(t+2) + stage(t+3)
        if (t + 3 < nk)      asm volatile("s_waitcnt vmcnt(8)" ::: "memory");
        else if (t + 2 < nk) asm volatile("s_waitcnt vmcnt(4)" ::: "memory");
        else if (t + 1 < nk) asm volatile("s_waitcnt vmcnt(0)" ::: "memory");
      }
      __builtin_amdgcn_s_barrier();
      __builtin_amdgcn_sched_barrier(0);
      __builtin_amdgcn_s_setprio(1);
#pragma unroll
      for (int m = 0; m < 4; ++m)
#pragma unroll
        for (int n = 0; n < 4; ++n)
          acc[p * 4 + m][n] = __builtin_amdgcn_mfma_f32_16x16x32_bf16(
              af[m], bfr[n], acc[p * 4 + m][n], 0, 0, 0);
      __builtin_amdgcn_s_setprio(0);
      __builtin_amdgcn_sched_barrier(0);
    }
  }

  float bv[4];
#pragma unroll
  for (int nf = 0; nf < 4; ++nf) bv[nf] = bias[bn + wcol * 64 + nf * 16 + lr];
#pragma unroll
  for (int mf = 0; mf < 8; ++mf) {
    const int row0 = bm + wr * 128 + mf * 16 + lg * 4;
#pragma unroll
    for (int nf = 0; nf < 4; ++nf) {
      const int col = bn + wcol * 64 + nf * 16 + lr;
#pragma unroll
      for (int r = 0; r < 4; ++r)
        C[(size_t)(row0 + r) * N + col] = acc[mf][nf][r] + bv[nf];
    }
  }
}

// ---------------- swapped-QK^T flash attention (round-14 exact: 3-ring, 1 barrier) -----
__global__ __launch_bounds__(256, 3) void attn_flash(
    const u16* __restrict__ Q,   // [8192, 768] bf16, pre-scaled
    const u16* __restrict__ Kb,  // [1024, 768] bf16 (rows >= 1000 are zero-padded)
    const u16* __restrict__ VT,  // [768, 1024] bf16
    u16* __restrict__ O) {       // [8192, 768] bf16
  constexpr int DM = 768, SPAD = 1024;
  __shared__ u16 Ks[3][64 * 64];    // 3 x 8 KB
  __shared__ u16 VTs[3][64 * 64];   // 3 x 8 KB

  const int tid = threadIdx.x, w = tid >> 6, lane = tid & 63;
  const int q5 = lane & 31, hi = lane >> 5, l7 = lane & 7;
  const int h = blockIdx.y;
  const int qrow = blockIdx.x * 128 + w * 32 + q5;

  bf16x8 qf[4];
#pragma unroll
  for (int dstep = 0; dstep < 4; ++dstep)
    qf[dstep] = *(const bf16x8*)(Q + (size_t)qrow * DM + h * 64 + dstep * 16 + hi * 8);

  auto STAGE = [&](int ch, int buf) {
#pragma unroll
    for (int it = 0; it < 2; ++it) {
      int slot = it * 256 + w * 64 + lane;
      int row = slot >> 3;
      int cg = (slot & 7) ^ (row & 7);
      __builtin_amdgcn_global_load_lds(
          (gld_src_t)(const void*)(Kb + (size_t)(ch * 64 + row) * DM + h * 64 + cg * 8),
          (gld_dst_t)(&Ks[buf][(size_t)(it * 256 + w * 64) * 8]), 16, 0, 0);
      __builtin_amdgcn_global_load_lds(
          (gld_src_t)(const void*)(VT + (size_t)(h * 64 + row) * SPAD + ch * 64 + cg * 8),
          (gld_dst_t)(&VTs[buf][(size_t)(it * 256 + w * 64) * 8]), 16, 0, 0);
    }
  };

  STAGE(0, 0);
  STAGE(1, 1);

  float m_run = -3.0e38f, l_part = 0.0f;
  f32x16 oa0 = {}, oa1 = {};

  for (int ch = 0; ch < 16; ++ch) {
    const int cur = ch % 3;
    if (ch < 15) asm volatile("s_waitcnt vmcnt(4)" ::: "memory");   // stage(ch) landed
    else         asm volatile("s_waitcnt vmcnt(0)" ::: "memory");
    __builtin_amdgcn_s_barrier();
    __builtin_amdgcn_sched_barrier(0);

    const char* kbase = (const char*)&Ks[cur][0];
    const char* vbase = (const char*)&VTs[cur][0];

    f32x16 sc0 = {}, sc1 = {};
#pragma unroll
    for (int dstep = 0; dstep < 4; ++dstep) {
      const int colb = (dstep * 32 + hi * 16);
      bf16x8 kf0 = *(const bf16x8*)(kbase + (size_t)q5 * 128 + (colb ^ (l7 << 4)));
      bf16x8 kf1 = *(const bf16x8*)(kbase + (size_t)(32 + q5) * 128 + (colb ^ (l7 << 4)));
      sc0 = __builtin_amdgcn_mfma_f32_32x32x16_bf16(kf0, qf[dstep], sc0, 0, 0, 0);
      sc1 = __builtin_amdgcn_mfma_f32_32x32x16_bf16(kf1, qf[dstep], sc1, 0, 0, 0);
    }
    if (ch == 15) {   // mask s >= 1000 (chunk 15, tile 1, regs r>=4)
#pragma unroll
      for (int r = 4; r < 16; ++r) sc1[r] = -3.0e38f;
    }

    float mi = sc0[0];
#pragma unroll
    for (int r = 1; r < 16; ++r) mi = fmaxf(mi, sc0[r]);
#pragma unroll
    for (int r = 0; r < 16; ++r) mi = fmaxf(mi, sc1[r]);
    float cm = fmaxf(mi, __shfl_xor(mi, 32, 64));

    if (__any(cm > m_run + 8.0f)) {        // defer-max (T13)
      float mn = fmaxf(m_run, cm);
      float fsc = exp2_fast(m_run - mn);
      m_run = mn;
      l_part *= fsc;
#pragma unroll
      for (int r = 0; r < 16; ++r) { oa0[r] *= fsc; oa1[r] *= fsc; }
    }

#pragma unroll
    for (int r = 0; r < 16; ++r) {
      float p0 = exp2_fast(sc0[r] - m_run); l_part += p0; sc0[r] = p0;
      float p1 = exp2_fast(sc1[r] - m_run); l_part += p1; sc1[r] = p1;
    }

#pragma unroll
    for (int st = 0; st < 2; ++st) {
#pragma unroll
      for (int ks = 0; ks < 2; ++ks) {
        float pv0, pv1, pv2, pv3, pv4, pv5, pv6, pv7;
        if (st == 0) {
          if (ks == 0) { pv0=sc0[0];pv1=sc0[1];pv2=sc0[2];pv3=sc0[3];pv4=sc0[4];pv5=sc0[5];pv6=sc0[6];pv7=sc0[7]; }
          else         { pv0=sc0[8];pv1=sc0[9];pv2=sc0[10];pv3=sc0[11];pv4=sc0[12];pv5=sc0[13];pv6=sc0[14];pv7=sc0[15]; }
        } else {
          if (ks == 0) { pv0=sc1[0];pv1=sc1[1];pv2=sc1[2];pv3=sc1[3];pv4=sc1[4];pv5=sc1[5];pv6=sc1[6];pv7=sc1[7]; }
          else         { pv0=sc1[8];pv1=sc1[9];pv2=sc1[10];pv3=sc1[11];pv4=sc1[12];pv5=sc1[13];pv6=sc1[14];pv7=sc1[15]; }
        }
        uint32_t a = pk_bf16(pv0, pv1), b = pk_bf16(pv2, pv3);
        uint32_t c = pk_bf16(pv4, pv5), d = pk_bf16(pv6, pv7);
        uint32_t sa = (uint32_t)__shfl_xor((int)a, 32, 64);
        uint32_t sb = (uint32_t)__shfl_xor((int)b, 32, 64);
        uint32_t sc_ = (uint32_t)__shfl_xor((int)c, 32, 64);
        uint32_t sd = (uint32_t)__shfl_xor((int)d, 32, 64);
        u32x4 jw;
        jw[0] = hi ? sc_ : a;
        jw[1] = hi ? sd  : b;
        jw[2] = hi ? c   : sa;
        jw[3] = hi ? d   : sb;
        bf16x8 pB = __builtin_bit_cast(bf16x8, jw);
        const int colb = (st * 64 + ks * 32 + hi * 16);
#pragma unroll
        for (int dt = 0; dt < 2; ++dt) {
          bf16x8 vtf = *(const bf16x8*)(vbase + (size_t)(dt * 32 + q5) * 128 + (colb ^ (l7 << 4)));
          if (dt == 0) oa0 = __builtin_amdgcn_mfma_f32_32x32x16_bf16(vtf, pB, oa0, 0, 0, 0);
          else         oa1 = __builtin_amdgcn_mfma_f32_32x32x16_bf16(vtf, pB, oa1, 0, 0, 0);
        }
      }
    }

    if (ch + 2 < 16) STAGE(ch + 2, (ch + 2) % 3);   // after barrier: buf (ch-1)%3 is free
  }

  float ool = 1.0f / (l_part + __shfl_xor(l_part, 32, 64));
  u16* obase = O + (size_t)qrow * DM + h * 64;
#pragma unroll
  for (int dt = 0; dt < 2; ++dt) {
#pragma unroll
    for (int g = 0; g < 4; ++g) {
      float v0, v1, v2, v3;
      if (dt == 0) { v0 = oa0[4*g]; v1 = oa0[4*g+1]; v2 = oa0[4*g+2]; v3 = oa0[4*g+3]; }
      else         { v0 = oa1[4*g]; v1 = oa1[4*g+1]; v2 = oa1[4*g+2]; v3 = oa1[4*g+3]; }
      u32x2 st2;
      st2[0] = pk_bf16(v0 * ool, v1 * ool);
      st2[1] = pk_bf16(v2 * ool, v3 * ool);
      *(u32x2*)(obase + dt * 32 + g * 8 + hi * 4) = st2;
    }
  }
}

// ---------------- host ----------------
extern "C" void kernel_launch(void* const* d_in, const int* in_sizes, int n_in,
                              void* d_out, int out_size, void* d_ws, size_t ws_size,
                              hipStream_t stream) {
  (void)in_sizes; (void)n_in; (void)out_size; (void)ws_size;
  const float* target = (const float*)d_in[0];
  const float* source = (const float*)d_in[1];
  const float* value  = (const float*)d_in[2];
  const float* Wq = (const float*)d_in[3];
  const float* bq = (const float*)d_in[4];
  const float* Wk = (const float*)d_in[5];
  const float* bk = (const float*)d_in[6];
  const float* Wv = (const float*)d_in[7];
  const float* bv = (const float*)d_in[8];
  const float* Wo = (const float*)d_in[9];
  const float* bo = (const float*)d_in[10];
  float* out = (float*)d_out;

  char* ws = (char*)d_ws;
  size_t off = 0;
  auto carve = [&](size_t bytes) { void* p = ws + off; off += (bytes + 255) & ~(size_t)255; return p; };
  u16* Xb  = (u16*)carve(8192ull * 768 * 2);
  u16* Sb  = (u16*)carve(1024ull * 4096 * 2);
  u16* Vbi = (u16*)carve(1024ull * 4096 * 2);
  u16* WqT = (u16*)carve(768ull * 768 * 2);
  u16* WkT = (u16*)carve(768ull * 4096 * 2);
  u16* WvT = (u16*)carve(768ull * 4096 * 2);
  u16* WoT = (u16*)carve(4096ull * 768 * 2);
  u16* Qb  = (u16*)carve(8192ull * 768 * 2);
  u16* Kp  = (u16*)carve(1024ull * 768 * 2);
  u16* VTp = (u16*)carve(768ull * 1024 * 2);
  u16* Ob  = (u16*)carve(8192ull * 768 * 2);

  const float SCL = 0.18033688011112042f;   // (1/8) * log2(e): exp2-domain scores

  preprocess_all<<<12864, 256, 0, stream>>>(target, Xb, source, Sb, value, Vbi,
                                            Wq, WqT, Wk, WkT, Wv, WvT, Wo, WoT);

  qkv_proj_fused<<<768, 256, 0, stream>>>(Xb, Sb, Vbi, WqT, WkT, WvT, bq, out, Qb, SCL);

  kv_reduce_all<<<1536, 256, 0, stream>>>(out, bk, bv, Kp, VTp);

  attn_flash<<<dim3(64, 12), 256, 0, stream>>>(Qb, Kp, VTp, Ob);

  gemm_bt_256p<<<dim3(16, 32), 512, 0, stream>>>(Ob, WoT, bo, out, 4096, 768);
}

// Round 19
// 186.295 us; speedup vs baseline: 1.2186x; 1.0014x over previous
//
#include <hip/hip_runtime.h>
#include <cstdint>
#include <type_traits>

// ReprogrammingLayer on MI355X (gfx950), round 19:
//  - single change vs round 18 (186.6 us): attention STAGE(ch+2) issued right after the
//    QK^T MFMAs (before softmax) instead of after PV -- T14 issue-early; loads get a
//    full softmax+PV+QKT of latency cover. Same buffers/barriers (r13 safety proof).

typedef unsigned short u16;
typedef __attribute__((ext_vector_type(8))) short bf16x8;    // 8 bf16 = 4 VGPR (MFMA A/B frag)
typedef __attribute__((ext_vector_type(4))) float f32x4;     // 16x16 MFMA C/D frag
typedef __attribute__((ext_vector_type(16))) float f32x16;   // 32x32 MFMA C/D frag
typedef __attribute__((ext_vector_type(4))) float fvec4;
typedef __attribute__((ext_vector_type(4))) unsigned short u16x4;
typedef __attribute__((ext_vector_type(4))) unsigned int u32x4;
typedef __attribute__((ext_vector_type(2))) unsigned int u32x2;

using gld_src_t = const __attribute__((address_space(1))) void*;
using gld_dst_t = __attribute__((address_space(3))) void*;

static __device__ __forceinline__ u16 bf16_rne(float f) {
  uint32_t u = __builtin_bit_cast(uint32_t, f);
  u += 0x7fffu + ((u >> 16) & 1u);          // round-to-nearest-even
  return (u16)(u >> 16);
}

static __device__ __forceinline__ float exp2_fast(float x) {
  float r; asm("v_exp_f32 %0, %1" : "=v"(r) : "v"(x)); return r;   // HW exp2
}

static __device__ __forceinline__ uint32_t pk_bf16(float a, float b) {
  return (uint32_t)bf16_rne(a) | ((uint32_t)bf16_rne(b) << 16);   // a -> low, b -> high
}

// ---------------- fused preprocessing: converts + all 4 weight transposes --------------
__global__ void preprocess_all(
    const float* __restrict__ target, u16* __restrict__ Xb,
    const float* __restrict__ source, u16* __restrict__ Sb,
    const float* __restrict__ value,  u16* __restrict__ Vbi,
    const float* __restrict__ Wq, u16* __restrict__ WqT,
    const float* __restrict__ Wk, u16* __restrict__ WkT,
    const float* __restrict__ Wv, u16* __restrict__ WvT,
    const float* __restrict__ Wo, u16* __restrict__ WoT) {
  __shared__ u16 tile[32][33];
  const int bi = blockIdx.x, tid = threadIdx.x;

  if (bi < 3072) {   // converts
    const int sel = bi >> 10;
    const int ib = bi & 1023;
    const float* in = sel == 0 ? target : (sel == 1 ? source : value);
    u16* out = sel == 0 ? Xb : (sel == 1 ? Sb : Vbi);
    const int C = sel == 0 ? 768 : 4096;
    const int validR = sel == 0 ? 8192 : 1000;
    const long n4 = sel == 0 ? (8192ll * 768 / 4) : (1024ll * 4096 / 4);
    const long stride = 1024ll * 256;
    for (long i = (long)ib * 256 + tid; i < n4; i += stride) {
      long e = i << 2;
      int r = (int)(e / C);
      u16x4 o;
      if (r < validR) {
        fvec4 v = *(const fvec4*)(in + e);
        o[0] = bf16_rne(v[0]); o[1] = bf16_rne(v[1]);
        o[2] = bf16_rne(v[2]); o[3] = bf16_rne(v[3]);
      } else {
        o[0] = 0; o[1] = 0; o[2] = 0; o[3] = 0;
      }
      *(u16x4*)(out + e) = o;
    }
    return;
  }

  int j = bi - 3072;
  const float* inv; u16* out; int R, C, bx, by;
  if (j < 576)        { inv = Wq; out = WqT; R = 768;  C = 768;  bx = j % 24;  by = j / 24; }
  else if (j < 3648)  { j -= 576;  inv = Wk; out = WkT; R = 4096; C = 768; bx = j % 24; by = j / 24; }
  else if (j < 6720)  { j -= 3648; inv = Wv; out = WvT; R = 4096; C = 768; bx = j % 24; by = j / 24; }
  else                { j -= 6720; inv = Wo; out = WoT; R = 768;  C = 4096; bx = j % 128; by = j / 128; }
  const int bc = bx * 32, br = by * 32;
  const int tx = tid & 31, ty = tid >> 5;
#pragma unroll
  for (int i = 0; i < 4; ++i) {
    int r = br + ty + i * 8, c = bc + tx;
    u16 bits = 0;
    if (r < R && c < C) bits = bf16_rne(inv[(size_t)r * C + c]);
    tile[ty + i * 8][tx] = bits;
  }
  __syncthreads();
#pragma unroll
  for (int i = 0; i < 4; ++i) {
    int orow = bc + ty + i * 8, oc = br + tx;
    if (orow < C && oc < R) out[(size_t)orow * R + oc] = tile[tx][ty + i * 8];
  }
}

// ---------------- fused Q-proj + split-K K/V proj (128p structure) ---------------------
__global__ __launch_bounds__(256, 2) void qkv_proj_fused(
    const u16* __restrict__ Xb, const u16* __restrict__ Sb, const u16* __restrict__ Vbi,
    const u16* __restrict__ WqT, const u16* __restrict__ WkT, const u16* __restrict__ WvT,
    const float* __restrict__ bq, float* __restrict__ part, u16* __restrict__ Qb,
    float scl) {
  __shared__ u16 As[2][128 * 64];
  __shared__ u16 Bs[2][128 * 64];

  const int tid = threadIdx.x, lane = tid & 63, w = tid >> 6;
  const int lr = lane & 15, lg = lane >> 4;
  const int wr = (w >> 1) * 64, wc = (w & 1) * 64;

  const int bi = blockIdx.x;
  const bool isQ = bi >= 384;
  const u16 *A, *B;
  int Kst, nk, kofs, bm, bn;
  float* Cf = nullptr;
  if (!isQ) {
    const int z = bi / 48, rem = bi % 48;
    bm = (rem / 6) * 128; bn = (rem % 6) * 128;
    A = (z >> 2) ? Vbi : Sb;
    B = (z >> 2) ? WvT : WkT;
    Cf = part + (size_t)z * 786432;
    kofs = (z & 3) * 1024; Kst = 4096; nk = 16;
  } else {
    const int j = bi - 384;
    const int swz = (j & 7) * 48 + (j >> 3);
    bm = (swz / 6) * 128; bn = (swz % 6) * 128;
    A = Xb; B = WqT; kofs = 0; Kst = 768; nk = 12;
  }

  f32x4 acc[4][4] = {};

  auto STAGE = [&](int t, int buf) {
#pragma unroll
    for (int it = 0; it < 4; ++it) {
      const int s = it * 256 + tid;
      const int r = s >> 3;
      const int cg = (s & 7) ^ (r & 7);
      const int ldsb = (it * 256 + w * 64) * 16;
      __builtin_amdgcn_global_load_lds(
          (gld_src_t)(const void*)(A + (size_t)(bm + r) * Kst + kofs + t * 64 + cg * 8),
          (gld_dst_t)((char*)&As[buf][0] + ldsb), 16, 0, 0);
      __builtin_amdgcn_global_load_lds(
          (gld_src_t)(const void*)(B + (size_t)(bn + r) * Kst + kofs + t * 64 + cg * 8),
          (gld_dst_t)((char*)&Bs[buf][0] + ldsb), 16, 0, 0);
    }
  };

  auto LDF = [&](const u16* base, int R, int CB) {
    return *(const bf16x8*)((const char*)base + (size_t)R * 128 + (CB ^ ((R & 7) << 4)));
  };

  STAGE(0, 0);

  for (int t = 0; t < nk; ++t) {
    const int cur = t & 1;
    if (t + 1 < nk) {
      STAGE(t + 1, cur ^ 1);
      asm volatile("s_waitcnt vmcnt(8)" ::: "memory");
    } else {
      asm volatile("s_waitcnt vmcnt(0)" ::: "memory");
    }
    __builtin_amdgcn_s_barrier();
    __builtin_amdgcn_sched_barrier(0);

    const u16* as = &As[cur][0];
    const u16* bs = &Bs[cur][0];

    bf16x8 af[4][2], bfr[4][2];
#pragma unroll
    for (int m = 0; m < 4; ++m)
#pragma unroll
      for (int kk = 0; kk < 2; ++kk)
        af[m][kk] = LDF(as, wr + m * 16 + lr, kk * 64 + lg * 16);
#pragma unroll
    for (int n = 0; n < 4; ++n)
#pragma unroll
      for (int kk = 0; kk < 2; ++kk)
        bfr[n][kk] = LDF(bs, wc + n * 16 + lr, kk * 64 + lg * 16);

    __builtin_amdgcn_s_setprio(1);
#pragma unroll
    for (int kk = 0; kk < 2; ++kk)
#pragma unroll
      for (int m = 0; m < 4; ++m)
#pragma unroll
        for (int n = 0; n < 4; ++n)
          acc[m][n] = __builtin_amdgcn_mfma_f32_16x16x32_bf16(
              af[m][kk], bfr[n][kk], acc[m][n], 0, 0, 0);
    __builtin_amdgcn_s_setprio(0);

    __builtin_amdgcn_sched_barrier(0);
    __builtin_amdgcn_s_barrier();
  }

  if (isQ) {
#pragma unroll
    for (int n = 0; n < 4; ++n) {
      const int col = bn + wc + n * 16 + lr;
      const float bv = bq[col];
#pragma unroll
      for (int m = 0; m < 4; ++m) {
        const int row0 = bm + wr + m * 16 + lg * 4;
#pragma unroll
        for (int r = 0; r < 4; ++r)
          Qb[(size_t)(row0 + r) * 768 + col] = bf16_rne((acc[m][n][r] + bv) * scl);
      }
    }
  } else {
#pragma unroll
    for (int n = 0; n < 4; ++n) {
      const int col = bn + wc + n * 16 + lr;
#pragma unroll
      for (int m = 0; m < 4; ++m) {
        const int row0 = bm + wr + m * 16 + lg * 4;
#pragma unroll
        for (int r = 0; r < 4; ++r)
          Cf[(size_t)(row0 + r) * 768 + col] = acc[m][n][r];
      }
    }
  }
}

// ---------------- fused reduces: blocks [0,768) K-reduce; [768,1536) V-reduce+transpose
__global__ __launch_bounds__(256) void kv_reduce_all(const float* __restrict__ part,
                                                     const float* __restrict__ bk,
                                                     const float* __restrict__ bv,
                                                     u16* __restrict__ Kp,
                                                     u16* __restrict__ VTp) {
  __shared__ u16 tile[32][33];
  const int bi = blockIdx.x;
  if (bi < 768) {
    const long e = ((long)bi * 256 + threadIdx.x) * 4;
    const float* p0 = part + e;
    fvec4 s = *(const fvec4*)p0;
    s += *(const fvec4*)(p0 + 786432);
    s += *(const fvec4*)(p0 + 2 * 786432);
    s += *(const fvec4*)(p0 + 3 * 786432);
    int col = (int)(e % 768);
    s += *(const fvec4*)(bk + col);
    u16x4 o;
    o[0] = bf16_rne(s[0]); o[1] = bf16_rne(s[1]); o[2] = bf16_rne(s[2]); o[3] = bf16_rne(s[3]);
    *(u16x4*)(Kp + e) = o;
    return;
  }
  const int j = bi - 768;
  const float* pv = part + 4ull * 786432;
  const int c0 = (j % 24) * 32, r0 = (j / 24) * 32;
  const int tx = threadIdx.x & 31, ty = threadIdx.x >> 5;
#pragma unroll
  for (int i = 0; i < 4; ++i) {
    const int r = r0 + ty + i * 8, c = c0 + tx;
    const size_t idx = (size_t)r * 768 + c;
    float s = pv[idx] + pv[idx + 786432] + pv[idx + 2 * 786432] + pv[idx + 3 * 786432]
            + bv[c];
    tile[ty + i * 8][tx] = bf16_rne(s);
  }
  __syncthreads();
#pragma unroll
  for (int i = 0; i < 4; ++i) {
    const int vr = c0 + ty + i * 8;
    const int vc = r0 + tx;
    VTp[(size_t)vr * 1024 + vc] = tile[tx][ty + i * 8];
  }
}

// ---------------- 256x256-tile BK=32 fine-phase GEMM, 3-deep prefetch (O-projection) ---
__global__ __launch_bounds__(512, 2) void gemm_bt_256p(
    const u16* __restrict__ A, const u16* __restrict__ B,
    const float* __restrict__ bias, float* __restrict__ C,
    int N, int K) {
  __shared__ u16 As[4][128 * 64];   // 4 x 16 KB
  __shared__ u16 Bs[4][128 * 64];   // 4 x 16 KB

  const int tid = threadIdx.x, lane = tid & 63, w = tid >> 6;
  const int lr = lane & 15, lg = lane >> 4;
  const int wr = w >> 2, wcol = w & 3;

  const int nbx = N >> 8;
  const int bid = blockIdx.y * gridDim.x + blockIdx.x;
  const int cpx = (gridDim.x * gridDim.y) >> 3;
  const int swz = (bid & 7) * cpx + (bid >> 3);
  const int bm = (swz / nbx) * 256, bn = (swz % nbx) * 256;

  f32x4 acc[8][4] = {};

  auto STAGE_UNIT = [&](int t, int buf, int mat) {
#pragma unroll
    for (int it = 0; it < 2; ++it) {
      const int s = it * 512 + tid;
      const int rp = s >> 3;
      const int cl = (s & 7) ^ (rp & 7);
      const int gr = (cl >> 2) * 128 + rp;
      const int gc = cl & 3;
      const int ldsb = (it * 512 + w * 64) * 16;
      const u16* src = (mat ? B : A) + (size_t)((mat ? bn : bm) + gr) * K + t * 32 + gc * 8;
      __builtin_amdgcn_global_load_lds((gld_src_t)(const void*)src,
          (gld_dst_t)((char*)(mat ? &Bs[buf][0] : &As[buf][0]) + ldsb), 16, 0, 0);
    }
  };

  auto LDF = [&](const u16* base, int gr, int klg) {
    const int byte = (gr & 127) * 128 + (((((gr >> 7) * 4 + klg) << 4)) ^ ((gr & 7) << 4));
    return *(const bf16x8*)((const char*)base + byte);
  };

  STAGE_UNIT(0, 0, 0); STAGE_UNIT(0, 0, 1);
  STAGE_UNIT(1, 1, 0); STAGE_UNIT(1, 1, 1);
  STAGE_UNIT(2, 2, 0); STAGE_UNIT(2, 2, 1);
  asm volatile("s_waitcnt vmcnt(8)" ::: "memory");
  __builtin_amdgcn_s_barrier();
  __builtin_amdgcn_sched_barrier(0);

  const int nk = K >> 5;   // 24
  bf16x8 bfr[4];
  for (int t = 0; t < nk; ++t) {
    const int cur = t & 3;
    const u16* as = &As[cur][0];
    const u16* bs = &Bs[cur][0];
#pragma unroll
    for (int p = 0; p < 2; ++p) {
      bf16x8 af[4];
#pragma unroll
      for (int m = 0; m < 4; ++m)
        af[m] = LDF(as, wr * 128 + (p * 4 + m) * 16 + lr, lg);
      if (p == 0) {
#pragma unroll
        for (int n = 0; n < 4; ++n)
          bfr[n] = LDF(bs, wcol * 64 + n * 16 + lr, lg);
      }
      if (t + 3 < nk) STAGE_UNIT(t + 3, (t + 3) & 3, p);
      if (p == 1) {
        if (t + 3 < nk)      asm volatile("s_waitcnt vmcnt(8)" ::: "memory");
        else if (t + 2 < nk) asm volatile("s_waitcnt vmcnt(4)" ::: "memory");
        else if (t + 1 < nk) asm volatile("s_waitcnt vmcnt(0)" ::: "memory");
      }
      __builtin_amdgcn_s_barrier();
      __builtin_amdgcn_sched_barrier(0);
      __builtin_amdgcn_s_setprio(1);
#pragma unroll
      for (int m = 0; m < 4; ++m)
#pragma unroll
        for (int n = 0; n < 4; ++n)
          acc[p * 4 + m][n] = __builtin_amdgcn_mfma_f32_16x16x32_bf16(
              af[m], bfr[n], acc[p * 4 + m][n], 0, 0, 0);
      __builtin_amdgcn_s_setprio(0);
      __builtin_amdgcn_sched_barrier(0);
    }
  }

  float bv[4];
#pragma unroll
  for (int nf = 0; nf < 4; ++nf) bv[nf] = bias[bn + wcol * 64 + nf * 16 + lr];
#pragma unroll
  for (int mf = 0; mf < 8; ++mf) {
    const int row0 = bm + wr * 128 + mf * 16 + lg * 4;
#pragma unroll
    for (int nf = 0; nf < 4; ++nf) {
      const int col = bn + wcol * 64 + nf * 16 + lr;
#pragma unroll
      for (int r = 0; r < 4; ++r)
        C[(size_t)(row0 + r) * N + col] = acc[mf][nf][r] + bv[nf];
    }
  }
}

// ---------------- swapped-QK^T flash attention: 3-ring, 1 barrier, issue-early STAGE ---
__global__ __launch_bounds__(256, 3) void attn_flash(
    const u16* __restrict__ Q,   // [8192, 768] bf16, pre-scaled
    const u16* __restrict__ Kb,  // [1024, 768] bf16 (rows >= 1000 are zero-padded)
    const u16* __restrict__ VT,  // [768, 1024] bf16
    u16* __restrict__ O) {       // [8192, 768] bf16
  constexpr int DM = 768, SPAD = 1024;
  __shared__ u16 Ks[3][64 * 64];    // 3 x 8 KB
  __shared__ u16 VTs[3][64 * 64];   // 3 x 8 KB

  const int tid = threadIdx.x, w = tid >> 6, lane = tid & 63;
  const int q5 = lane & 31, hi = lane >> 5, l7 = lane & 7;
  const int h = blockIdx.y;
  const int qrow = blockIdx.x * 128 + w * 32 + q5;

  bf16x8 qf[4];
#pragma unroll
  for (int dstep = 0; dstep < 4; ++dstep)
    qf[dstep] = *(const bf16x8*)(Q + (size_t)qrow * DM + h * 64 + dstep * 16 + hi * 8);

  auto STAGE = [&](int ch, int buf) {
#pragma unroll
    for (int it = 0; it < 2; ++it) {
      int slot = it * 256 + w * 64 + lane;
      int row = slot >> 3;
      int cg = (slot & 7) ^ (row & 7);
      __builtin_amdgcn_global_load_lds(
          (gld_src_t)(const void*)(Kb + (size_t)(ch * 64 + row) * DM + h * 64 + cg * 8),
          (gld_dst_t)(&Ks[buf][(size_t)(it * 256 + w * 64) * 8]), 16, 0, 0);
      __builtin_amdgcn_global_load_lds(
          (gld_src_t)(const void*)(VT + (size_t)(h * 64 + row) * SPAD + ch * 64 + cg * 8),
          (gld_dst_t)(&VTs[buf][(size_t)(it * 256 + w * 64) * 8]), 16, 0, 0);
    }
  };

  STAGE(0, 0);
  STAGE(1, 1);

  float m_run = -3.0e38f, l_part = 0.0f;
  f32x16 oa0 = {}, oa1 = {};

  for (int ch = 0; ch < 16; ++ch) {
    const int cur = ch % 3;
    if (ch < 14) asm volatile("s_waitcnt vmcnt(8)" ::: "memory");   // stage(ch) landed; ch+1, ch+2 may fly
    else if (ch < 15) asm volatile("s_waitcnt vmcnt(4)" ::: "memory");
    else         asm volatile("s_waitcnt vmcnt(0)" ::: "memory");
    __builtin_amdgcn_s_barrier();
    __builtin_amdgcn_sched_barrier(0);

    const char* kbase = (const char*)&Ks[cur][0];
    const char* vbase = (const char*)&VTs[cur][0];

    f32x16 sc0 = {}, sc1 = {};
#pragma unroll
    for (int dstep = 0; dstep < 4; ++dstep) {
      const int colb = (dstep * 32 + hi * 16);
      bf16x8 kf0 = *(const bf16x8*)(kbase + (size_t)q5 * 128 + (colb ^ (l7 << 4)));
      bf16x8 kf1 = *(const bf16x8*)(kbase + (size_t)(32 + q5) * 128 + (colb ^ (l7 << 4)));
      sc0 = __builtin_amdgcn_mfma_f32_32x32x16_bf16(kf0, qf[dstep], sc0, 0, 0, 0);
      sc1 = __builtin_amdgcn_mfma_f32_32x32x16_bf16(kf1, qf[dstep], sc1, 0, 0, 0);
    }

    // T14 issue-early: stage ch+2 NOW (target buf (ch+2)%3 == (ch-1)%3; its readers
    // finished before barrier_ch, which this wave already crossed). Loads get the
    // rest of this chunk (softmax+pack+PV) plus next chunk's QKT to land.
    if (ch + 2 < 16) STAGE(ch + 2, (ch + 2) % 3);

    if (ch == 15) {   // mask s >= 1000 (chunk 15, tile 1, regs r>=4)
#pragma unroll
      for (int r = 4; r < 16; ++r) sc1[r] = -3.0e38f;
    }

    float mi = sc0[0];
#pragma unroll
    for (int r = 1; r < 16; ++r) mi = fmaxf(mi, sc0[r]);
#pragma unroll
    for (int r = 0; r < 16; ++r) mi = fmaxf(mi, sc1[r]);
    float cm = fmaxf(mi, __shfl_xor(mi, 32, 64));

    if (__any(cm > m_run + 8.0f)) {        // defer-max (T13)
      float mn = fmaxf(m_run, cm);
      float fsc = exp2_fast(m_run - mn);
      m_run = mn;
      l_part *= fsc;
#pragma unroll
      for (int r = 0; r < 16; ++r) { oa0[r] *= fsc; oa1[r] *= fsc; }
    }

#pragma unroll
    for (int r = 0; r < 16; ++r) {
      float p0 = exp2_fast(sc0[r] - m_run); l_part += p0; sc0[r] = p0;
      float p1 = exp2_fast(sc1[r] - m_run); l_part += p1; sc1[r] = p1;
    }

#pragma unroll
    for (int st = 0; st < 2; ++st) {
#pragma unroll
      for (int ks = 0; ks < 2; ++ks) {
        float pv0, pv1, pv2, pv3, pv4, pv5, pv6, pv7;
        if (st == 0) {
          if (ks == 0) { pv0=sc0[0];pv1=sc0[1];pv2=sc0[2];pv3=sc0[3];pv4=sc0[4];pv5=sc0[5];pv6=sc0[6];pv7=sc0[7]; }
          else         { pv0=sc0[8];pv1=sc0[9];pv2=sc0[10];pv3=sc0[11];pv4=sc0[12];pv5=sc0[13];pv6=sc0[14];pv7=sc0[15]; }
        } else {
          if (ks == 0) { pv0=sc1[0];pv1=sc1[1];pv2=sc1[2];pv3=sc1[3];pv4=sc1[4];pv5=sc1[5];pv6=sc1[6];pv7=sc1[7]; }
          else         { pv0=sc1[8];pv1=sc1[9];pv2=sc1[10];pv3=sc1[11];pv4=sc1[12];pv5=sc1[13];pv6=sc1[14];pv7=sc1[15]; }
        }
        uint32_t a = pk_bf16(pv0, pv1), b = pk_bf16(pv2, pv3);
        uint32_t c = pk_bf16(pv4, pv5), d = pk_bf16(pv6, pv7);
        uint32_t sa = (uint32_t)__shfl_xor((int)a, 32, 64);
        uint32_t sb = (uint32_t)__shfl_xor((int)b, 32, 64);
        uint32_t sc_ = (uint32_t)__shfl_xor((int)c, 32, 64);
        uint32_t sd = (uint32_t)__shfl_xor((int)d, 32, 64);
        u32x4 jw;
        jw[0] = hi ? sc_ : a;
        jw[1] = hi ? sd  : b;
        jw[2] = hi ? c   : sa;
        jw[3] = hi ? d   : sb;
        bf16x8 pB = __builtin_bit_cast(bf16x8, jw);
        const int colb = (st * 64 + ks * 32 + hi * 16);
#pragma unroll
        for (int dt = 0; dt < 2; ++dt) {
          bf16x8 vtf = *(const bf16x8*)(vbase + (size_t)(dt * 32 + q5) * 128 + (colb ^ (l7 << 4)));
          if (dt == 0) oa0 = __builtin_amdgcn_mfma_f32_32x32x16_bf16(vtf, pB, oa0, 0, 0, 0);
          else         oa1 = __builtin_amdgcn_mfma_f32_32x32x16_bf16(vtf, pB, oa1, 0, 0, 0);
        }
      }
    }
  }

  float ool = 1.0f / (l_part + __shfl_xor(l_part, 32, 64));
  u16* obase = O + (size_t)qrow * DM + h * 64;
#pragma unroll
  for (int dt = 0; dt < 2; ++dt) {
#pragma unroll
    for (int g = 0; g < 4; ++g) {
      float v0, v1, v2, v3;
      if (dt == 0) { v0 = oa0[4*g]; v1 = oa0[4*g+1]; v2 = oa0[4*g+2]; v3 = oa0[4*g+3]; }
      else         { v0 = oa1[4*g]; v1 = oa1[4*g+1]; v2 = oa1[4*g+2]; v3 = oa1[4*g+3]; }
      u32x2 st2;
      st2[0] = pk_bf16(v0 * ool, v1 * ool);
      st2[1] = pk_bf16(v2 * ool, v3 * ool);
      *(u32x2*)(obase + dt * 32 + g * 8 + hi * 4) = st2;
    }
  }
}

// ---------------- host ----------------
extern "C" void kernel_launch(void* const* d_in, const int* in_sizes, int n_in,
                              void* d_out, int out_size, void* d_ws, size_t ws_size,
                              hipStream_t stream) {
  (void)in_sizes; (void)n_in; (void)out_size; (void)ws_size;
  const float* target = (const float*)d_in[0];
  const float* source = (const float*)d_in[1];
  const float* value  = (const float*)d_in[2];
  const float* Wq = (const float*)d_in[3];
  const float* bq = (const float*)d_in[4];
  const float* Wk = (const float*)d_in[5];
  const float* bk = (const float*)d_in[6];
  const float* Wv = (const float*)d_in[7];
  const float* bv = (const float*)d_in[8];
  const float* Wo = (const float*)d_in[9];
  const float* bo = (const float*)d_in[10];
  float* out = (float*)d_out;

  char* ws = (char*)d_ws;
  size_t off = 0;
  auto carve = [&](size_t bytes) { void* p = ws + off; off += (bytes + 255) & ~(size_t)255; return p; };
  u16* Xb  = (u16*)carve(8192ull * 768 * 2);
  u16* Sb  = (u16*)carve(1024ull * 4096 * 2);
  u16* Vbi = (u16*)carve(1024ull * 4096 * 2);
  u16* WqT = (u16*)carve(768ull * 768 * 2);
  u16* WkT = (u16*)carve(768ull * 4096 * 2);
  u16* WvT = (u16*)carve(768ull * 4096 * 2);
  u16* WoT = (u16*)carve(4096ull * 768 * 2);
  u16* Qb  = (u16*)carve(8192ull * 768 * 2);
  u16* Kp  = (u16*)carve(1024ull * 768 * 2);
  u16* VTp = (u16*)carve(768ull * 1024 * 2);
  u16* Ob  = (u16*)carve(8192ull * 768 * 2);

  const float SCL = 0.18033688011112042f;   // (1/8) * log2(e): exp2-domain scores

  preprocess_all<<<12864, 256, 0, stream>>>(target, Xb, source, Sb, value, Vbi,
                                            Wq, WqT, Wk, WkT, Wv, WvT, Wo, WoT);

  qkv_proj_fused<<<768, 256, 0, stream>>>(Xb, Sb, Vbi, WqT, WkT, WvT, bq, out, Qb, SCL);

  kv_reduce_all<<<1536, 256, 0, stream>>>(out, bk, bv, Kp, VTp);

  attn_flash<<<dim3(64, 12), 256, 0, stream>>>(Qb, Kp, VTp, Ob);

  gemm_bt_256p<<<dim3(16, 32), 512, 0, stream>>>(Ob, WoT, bo, out, 4096, 768);
}